// Round 1
// baseline (430.444 us; speedup 1.0000x reference)
//
#include <hip/hip_runtime.h>
#include <math.h>

#define NN 16384
#define TILE_M 64
#define LDA 132   // 128 + 4 pad (keeps float4 LDS alignment, breaks pow2 strides)

// Generic 64x128 = (64x128)@(128x128) tile GEMM.
// A in LDS (lda=LDA), W global row-major [128][128] (streamed via L1/L2).
// Thread t computes 4 rows x 8 cols. 256 threads.
template<bool PRE_RELU, bool POST_RELU, bool HAS_BIAS, bool HAS_ADD, bool TO_LDS, bool TO_GLOBAL>
__device__ __forceinline__ void gemm_tile(
    const float* As, const float* __restrict__ W,
    const float* __restrict__ bias, const float* __restrict__ addv,
    float* Cs, float* __restrict__ Cg, int node0, int t)
{
    const int m0 = (t >> 4) * 4;
    const int c0 = (t & 15) * 8;
    float acc[4][8];
#pragma unroll
    for (int mm = 0; mm < 4; ++mm)
#pragma unroll
        for (int cc = 0; cc < 8; ++cc) acc[mm][cc] = 0.f;

#pragma unroll 2
    for (int ic = 0; ic < 32; ++ic) {
        float a[4][4];
#pragma unroll
        for (int mm = 0; mm < 4; ++mm) {
            float4 av = *(const float4*)&As[(m0 + mm) * LDA + ic * 4];
            a[mm][0] = av.x; a[mm][1] = av.y; a[mm][2] = av.z; a[mm][3] = av.w;
            if (PRE_RELU) {
#pragma unroll
                for (int ii = 0; ii < 4; ++ii) a[mm][ii] = fmaxf(a[mm][ii], 0.f);
            }
        }
        float w[4][8];
#pragma unroll
        for (int ii = 0; ii < 4; ++ii) {
            float4 w0 = *(const float4*)&W[(ic * 4 + ii) * 128 + c0];
            float4 w1 = *(const float4*)&W[(ic * 4 + ii) * 128 + c0 + 4];
            w[ii][0] = w0.x; w[ii][1] = w0.y; w[ii][2] = w0.z; w[ii][3] = w0.w;
            w[ii][4] = w1.x; w[ii][5] = w1.y; w[ii][6] = w1.z; w[ii][7] = w1.w;
        }
#pragma unroll
        for (int mm = 0; mm < 4; ++mm)
#pragma unroll
            for (int ii = 0; ii < 4; ++ii) {
                float av = a[mm][ii];
#pragma unroll
                for (int cc = 0; cc < 8; ++cc)
                    acc[mm][cc] = fmaf(av, w[ii][cc], acc[mm][cc]);
            }
    }

    float bb[8];
    if (HAS_BIAS) {
#pragma unroll
        for (int cc = 0; cc < 8; ++cc) bb[cc] = bias[c0 + cc];
    }
#pragma unroll
    for (int mm = 0; mm < 4; ++mm) {
        float v[8];
#pragma unroll
        for (int cc = 0; cc < 8; ++cc) {
            float x = acc[mm][cc];
            if (HAS_BIAS) x += bb[cc];
            if (POST_RELU) x = fmaxf(x, 0.f);
            v[cc] = x;
        }
        if (HAS_ADD) {
            float4 a0 = *(const float4*)&addv[(size_t)(node0 + m0 + mm) * 128 + c0];
            float4 a1 = *(const float4*)&addv[(size_t)(node0 + m0 + mm) * 128 + c0 + 4];
            v[0] += a0.x; v[1] += a0.y; v[2] += a0.z; v[3] += a0.w;
            v[4] += a1.x; v[5] += a1.y; v[6] += a1.z; v[7] += a1.w;
        }
        if (TO_LDS) {
#pragma unroll
            for (int cc = 0; cc < 8; ++cc) Cs[(m0 + mm) * LDA + c0 + cc] = v[cc];
        }
        if (TO_GLOBAL) {
            float4 s0 = make_float4(v[0], v[1], v[2], v[3]);
            float4 s1 = make_float4(v[4], v[5], v[6], v[7]);
            *(float4*)&Cg[(size_t)(node0 + m0 + mm) * 128 + c0] = s0;
            *(float4*)&Cg[(size_t)(node0 + m0 + mm) * 128 + c0 + 4] = s1;
        }
    }
}

// Fused per-node linear algebra: q, 3-layer MLP -> msg, msgk, msgv.
// msg never goes to global (only its projections are needed, via gather-commute).
__global__ __launch_bounds__(256) void phaseA_kernel(
    const float* __restrict__ features, const float* __restrict__ enc,
    const float* __restrict__ W1, const float* __restrict__ b1,
    const float* __restrict__ W2, const float* __restrict__ b2,
    const float* __restrict__ W3, const float* __restrict__ b3,
    const float* __restrict__ Wq, const float* __restrict__ bq,
    const float* __restrict__ Wk, const float* __restrict__ Wv,
    float* __restrict__ qout, float* __restrict__ msgk, float* __restrict__ msgv)
{
    __shared__ __align__(16) float bufF[TILE_M * LDA];
    __shared__ __align__(16) float bufB[TILE_M * LDA];
    const int t = threadIdx.x;
    const int node0 = blockIdx.x * TILE_M;

#pragma unroll
    for (int r = 0; r < 8; ++r) {
        int fid = t + 256 * r;
        int row = fid >> 5;
        int c4 = (fid & 31) * 4;
        float4 v = *(const float4*)&features[(size_t)(node0 + row) * 128 + c4];
        *(float4*)&bufF[row * LDA + c4] = v;
    }
    __syncthreads();
    // q = F @ Wq + bq (raw features)
    gemm_tile<false, false, true, false, false, true>(bufF, Wq, bq, nullptr, nullptr, qout, node0, t);
    // h1 = relu(relu(F) @ W1 + b1) -> bufB
    gemm_tile<true, true, true, false, true, false>(bufF, W1, b1, nullptr, bufB, nullptr, node0, t);
    __syncthreads();
    // h2 = relu(h1 @ W2 + b2) -> bufF (F dead: q and h1 reads done before this sync)
    gemm_tile<false, true, true, false, true, false>(bufB, W2, b2, nullptr, bufF, nullptr, node0, t);
    __syncthreads();
    // msg = relu(h2 @ W3 + b3) + enc -> bufB
    gemm_tile<false, true, true, true, true, false>(bufF, W3, b3, enc, bufB, nullptr, node0, t);
    __syncthreads();
    // msgk = msg @ Wk[:128]  (bk dropped: softmax-invariant)
    gemm_tile<false, false, false, false, false, true>(bufB, Wk, nullptr, nullptr, nullptr, msgk, node0, t);
    // msgv = msg @ Wv[:128]  (bv applied in attention epilogue)
    gemm_tile<false, false, false, false, false, true>(bufB, Wv, nullptr, nullptr, nullptr, msgv, node0, t);
}

// One block per node. Threads: logits phase uses t = h*32+k (half-wave softmax);
// output phase uses t = h*16+a for the 128 output features.
__global__ __launch_bounds__(256) void attn_kernel(
    const float* __restrict__ qg, const float* __restrict__ msgk,
    const float* __restrict__ msgv, const float* __restrict__ dist,
    const float* __restrict__ seq, const int* __restrict__ idx,
    const float* __restrict__ Wk, const float* __restrict__ Wv,
    const float* __restrict__ bv, float* __restrict__ outp)
{
    __shared__ __align__(16) float qs[128];
    __shared__ float dists[32 * 33];   // +1 pad: kills stride-32 conflicts
    __shared__ float seqs[32 * 17];
    __shared__ int   idxs[32];
    __shared__ float qkd_s[8 * 32];
    __shared__ float qks_s[8 * 16];
    __shared__ float attn_s[256];
    __shared__ float wd_s[256];
    __shared__ float ws_s[128];

    const int t = threadIdx.x;
    const int n = blockIdx.x;

    {
        float4 v = *(const float4*)&dist[(size_t)n * 1024 + t * 4];
        int k = t >> 3, d0 = (t & 7) * 4;
        dists[k * 33 + d0 + 0] = v.x; dists[k * 33 + d0 + 1] = v.y;
        dists[k * 33 + d0 + 2] = v.z; dists[k * 33 + d0 + 3] = v.w;
    }
    if (t < 128) {
        float4 v = *(const float4*)&seq[(size_t)n * 512 + t * 4];
        int k = t >> 2, s0 = (t & 3) * 4;
        seqs[k * 17 + s0 + 0] = v.x; seqs[k * 17 + s0 + 1] = v.y;
        seqs[k * 17 + s0 + 2] = v.z; seqs[k * 17 + s0 + 3] = v.w;
        qs[t] = qg[(size_t)n * 128 + t];
    }
    if (t < 32) idxs[t] = idx[n * 32 + t];
    __syncthreads();

    // qkd[h][d] = sum_a q[h,a] * Wk[128+d][h*16+a] — coalesced load + 16-lane shfl reduce
#pragma unroll
    for (int r = 0; r < 16; ++r) {
        int f = t + 256 * r;          // flat index into Wk_dist [32][128]
        int c = f & 127;
        int d = f >> 7;
        float p = Wk[(128 + d) * 128 + c] * qs[c];
#pragma unroll
        for (int off = 8; off; off >>= 1) p += __shfl_xor(p, off);
        if ((t & 15) == 0) qkd_s[(c >> 4) * 32 + d] = p;
    }
    // qks[h][s] likewise over Wk_seq [16][128]
#pragma unroll
    for (int r = 0; r < 8; ++r) {
        int f = t + 256 * r;
        int c = f & 127;
        int s = f >> 7;
        float p = Wk[(160 + s) * 128 + c] * qs[c];
#pragma unroll
        for (int off = 8; off; off >>= 1) p += __shfl_xor(p, off);
        if ((t & 15) == 0) qks_s[(c >> 4) * 16 + s] = p;
    }
    __syncthreads();

    // logits + softmax over K (32 lanes = one head)
    {
        int h = t >> 5, k = t & 31;
        int j = idxs[k];
        const float* mk = &msgk[(size_t)j * 128 + h * 16];
        float4 q0 = *(const float4*)&qs[h * 16];
        float4 q1 = *(const float4*)&qs[h * 16 + 4];
        float4 q2 = *(const float4*)&qs[h * 16 + 8];
        float4 q3 = *(const float4*)&qs[h * 16 + 12];
        float4 m0 = *(const float4*)&mk[0];
        float4 m1 = *(const float4*)&mk[4];
        float4 m2 = *(const float4*)&mk[8];
        float4 m3 = *(const float4*)&mk[12];
        float lg = q0.x * m0.x + q0.y * m0.y + q0.z * m0.z + q0.w * m0.w
                 + q1.x * m1.x + q1.y * m1.y + q1.z * m1.z + q1.w * m1.w
                 + q2.x * m2.x + q2.y * m2.y + q2.z * m2.z + q2.w * m2.w
                 + q3.x * m3.x + q3.y * m3.y + q3.z * m3.z + q3.w * m3.w;
#pragma unroll
        for (int d = 0; d < 32; ++d) lg += dists[k * 33 + d] * qkd_s[h * 32 + d];
#pragma unroll
        for (int s = 0; s < 16; ++s) lg += seqs[k * 17 + s] * qks_s[h * 16 + s];
        lg *= 0.25f;  // 1/sqrt(ADIM=16)
        float mx = lg;
#pragma unroll
        for (int off = 16; off; off >>= 1) mx = fmaxf(mx, __shfl_xor(mx, off));
        float e = __expf(lg - mx);
        float sum = e;
#pragma unroll
        for (int off = 16; off; off >>= 1) sum += __shfl_xor(sum, off);
        attn_s[t] = e / sum;   // attn_s[h*32+k]
    }
    __syncthreads();

    // o[h,a] = sum_k attn * msgv[j_k][h*16+a]  (coalesced row reads)
    float o = 0.f;
    if (t < 128) {
        int h = t >> 4;
#pragma unroll 4
        for (int k = 0; k < 32; ++k)
            o += attn_s[h * 32 + k] * msgv[(size_t)idxs[k] * 128 + t];
    }
    // wdist[h][d] = sum_k attn * dist[k][d]
    {
        int h = t >> 5, d = t & 31;
        float wd = 0.f;
#pragma unroll 4
        for (int k = 0; k < 32; ++k) wd += attn_s[h * 32 + k] * dists[k * 33 + d];
        wd_s[t] = wd;
    }
    if (t < 128) {
        int h = t >> 4, s = t & 15;
        float ws = 0.f;
#pragma unroll 4
        for (int k = 0; k < 32; ++k) ws += attn_s[h * 32 + k] * seqs[k * 17 + s];
        ws_s[t] = ws;
    }
    __syncthreads();
    if (t < 128) {
        int h = t >> 4;
        float val = o + bv[t];
#pragma unroll 4
        for (int d = 0; d < 32; ++d) val += wd_s[h * 32 + d] * Wv[(128 + d) * 128 + t];
#pragma unroll 4
        for (int s = 0; s < 16; ++s) val += ws_s[h * 16 + s] * Wv[(160 + s) * 128 + t];
        outp[(size_t)n * 128 + t] = val;
    }
}

// out = features + outp @ Wo + bo
__global__ __launch_bounds__(256) void final_kernel(
    const float* __restrict__ outp, const float* __restrict__ Wo,
    const float* __restrict__ bo, const float* __restrict__ features,
    float* __restrict__ out)
{
    __shared__ __align__(16) float buf[TILE_M * LDA];
    const int t = threadIdx.x;
    const int node0 = blockIdx.x * TILE_M;
#pragma unroll
    for (int r = 0; r < 8; ++r) {
        int fid = t + 256 * r;
        int row = fid >> 5;
        int c4 = (fid & 31) * 4;
        *(float4*)&buf[row * LDA + c4] =
            *(const float4*)&outp[(size_t)(node0 + row) * 128 + c4];
    }
    __syncthreads();
    gemm_tile<false, false, true, true, false, true>(buf, Wo, bo, features, nullptr, out, node0, t);
}

extern "C" void kernel_launch(void* const* d_in, const int* in_sizes, int n_in,
                              void* d_out, int out_size, void* d_ws, size_t ws_size,
                              hipStream_t stream)
{
    const float* features = (const float*)d_in[0];
    const float* dist     = (const float*)d_in[1];
    const float* seq      = (const float*)d_in[2];
    const float* enc      = (const float*)d_in[3];
    const int*   idx      = (const int*)d_in[4];
    const float* W1 = (const float*)d_in[5];
    const float* b1 = (const float*)d_in[6];
    const float* W2 = (const float*)d_in[7];
    const float* b2 = (const float*)d_in[8];
    const float* W3 = (const float*)d_in[9];
    const float* b3 = (const float*)d_in[10];
    const float* Wq = (const float*)d_in[11];
    const float* bq = (const float*)d_in[12];
    const float* Wk = (const float*)d_in[13];
    // d_in[14] = bk: dropped (constant per (n,h) logit shift -> softmax-invariant)
    const float* Wv = (const float*)d_in[15];
    const float* bv = (const float*)d_in[16];
    const float* Wo = (const float*)d_in[17];
    const float* bo = (const float*)d_in[18];
    float* out = (float*)d_out;

    float* qbuf = (float*)d_ws;
    float* msgk = qbuf + (size_t)NN * 128;
    float* msgv = msgk + (size_t)NN * 128;
    float* outp = msgv + (size_t)NN * 128;

    phaseA_kernel<<<NN / TILE_M, 256, 0, stream>>>(
        features, enc, W1, b1, W2, b2, W3, b3, Wq, bq, Wk, Wv, qbuf, msgk, msgv);
    attn_kernel<<<NN, 256, 0, stream>>>(
        qbuf, msgk, msgv, dist, seq, idx, Wk, Wv, bv, outp);
    final_kernel<<<NN / TILE_M, 256, 0, stream>>>(outp, Wo, bo, features, out);
}

// Round 2
// 374.263 us; speedup vs baseline: 1.1501x; 1.1501x over previous
//
#include <hip/hip_runtime.h>
#include <math.h>

#define NN 16384
#define TM 32
#define LDA 132   // 128 + 4 pad, float4-aligned

typedef unsigned int uint;
typedef unsigned short ushort;

__device__ __forceinline__ ushort f2bf(float x) {
    uint u = __float_as_uint(x);
    u += 0x7fffu + ((u >> 16) & 1u);   // RNE
    return (ushort)(u >> 16);
}
__device__ __forceinline__ float bflo(uint u) { return __uint_as_float(u << 16); }
__device__ __forceinline__ float bfhi(uint u) { return __uint_as_float(u & 0xffff0000u); }

// 32x128 = (32x128)@(128x128) tile GEMM, A in LDS, W global (L2-hot).
// 256 threads, per-thread 4 rows x 4 cols. MODE: 0=LDS out, 1=global f32, 2=kv bf16.
template<bool PRE_RELU, bool POST_RELU, bool HAS_BIAS, bool HAS_ENC, int MODE>
__device__ __forceinline__ void gemm32(
    const float* As, const float* __restrict__ W,
    const float* __restrict__ bias, const float* __restrict__ enc,
    float* Cs, float* __restrict__ Cg, ushort* __restrict__ kvg, int kvoff,
    int node0, int t)
{
    const int m0 = (t >> 5) * 4;
    const int c0 = (t & 31) * 4;
    float acc[4][4];
#pragma unroll
    for (int mm = 0; mm < 4; ++mm)
#pragma unroll
        for (int cc = 0; cc < 4; ++cc) acc[mm][cc] = 0.f;

#pragma unroll 4
    for (int ic = 0; ic < 32; ++ic) {
        float a[4][4];
#pragma unroll
        for (int mm = 0; mm < 4; ++mm) {
            float4 av = *(const float4*)&As[(m0 + mm) * LDA + ic * 4];
            a[mm][0] = av.x; a[mm][1] = av.y; a[mm][2] = av.z; a[mm][3] = av.w;
            if (PRE_RELU) {
#pragma unroll
                for (int ii = 0; ii < 4; ++ii) a[mm][ii] = fmaxf(a[mm][ii], 0.f);
            }
        }
        float w[4][4];
#pragma unroll
        for (int ii = 0; ii < 4; ++ii) {
            float4 wv = *(const float4*)&W[(ic * 4 + ii) * 128 + c0];
            w[ii][0] = wv.x; w[ii][1] = wv.y; w[ii][2] = wv.z; w[ii][3] = wv.w;
        }
#pragma unroll
        for (int mm = 0; mm < 4; ++mm)
#pragma unroll
            for (int ii = 0; ii < 4; ++ii) {
                float av = a[mm][ii];
#pragma unroll
                for (int cc = 0; cc < 4; ++cc)
                    acc[mm][cc] = fmaf(av, w[ii][cc], acc[mm][cc]);
            }
    }

    float bb[4];
    if (HAS_BIAS) {
        float4 bvv = *(const float4*)&bias[c0];
        bb[0] = bvv.x; bb[1] = bvv.y; bb[2] = bvv.z; bb[3] = bvv.w;
    }
#pragma unroll
    for (int mm = 0; mm < 4; ++mm) {
        float v[4];
#pragma unroll
        for (int cc = 0; cc < 4; ++cc) {
            float x = acc[mm][cc];
            if (HAS_BIAS) x += bb[cc];
            if (POST_RELU) x = fmaxf(x, 0.f);
            v[cc] = x;
        }
        if (HAS_ENC) {
            float4 e4 = *(const float4*)&enc[(size_t)(node0 + m0 + mm) * 128 + c0];
            v[0] += e4.x; v[1] += e4.y; v[2] += e4.z; v[3] += e4.w;
        }
        if (MODE == 0) {
            *(float4*)&Cs[(m0 + mm) * LDA + c0] = make_float4(v[0], v[1], v[2], v[3]);
        } else if (MODE == 1) {
            *(float4*)&Cg[(size_t)(node0 + m0 + mm) * 128 + c0] = make_float4(v[0], v[1], v[2], v[3]);
        } else {
            uint lo = (uint)f2bf(v[0]) | ((uint)f2bf(v[1]) << 16);
            uint hi = (uint)f2bf(v[2]) | ((uint)f2bf(v[3]) << 16);
            *(uint2*)&kvg[(size_t)(node0 + m0 + mm) * 256 + kvoff + c0] = make_uint2(lo, hi);
        }
    }
}

// q + 3-layer MLP -> msg -> {msgk|msgv} bf16 interleaved table. 32 nodes/block.
__global__ __launch_bounds__(256) void phaseA_kernel(
    const float* __restrict__ features, const float* __restrict__ enc,
    const float* __restrict__ W1, const float* __restrict__ b1,
    const float* __restrict__ W2, const float* __restrict__ b2,
    const float* __restrict__ W3, const float* __restrict__ b3,
    const float* __restrict__ Wq, const float* __restrict__ bq,
    const float* __restrict__ Wk, const float* __restrict__ Wv,
    float* __restrict__ qout, ushort* __restrict__ kv)
{
    __shared__ __align__(16) float bufF[TM * LDA];
    __shared__ __align__(16) float bufB[TM * LDA];
    const int t = threadIdx.x;
    const int node0 = blockIdx.x * TM;

#pragma unroll
    for (int r = 0; r < 4; ++r) {
        int fid = t + 256 * r;
        int row = fid >> 5, c4 = (fid & 31) * 4;
        *(float4*)&bufF[row * LDA + c4] =
            *(const float4*)&features[(size_t)(node0 + row) * 128 + c4];
    }
    __syncthreads();
    gemm32<false, false, true, false, 1>(bufF, Wq, bq, nullptr, nullptr, qout, nullptr, 0, node0, t);
    gemm32<true,  true,  true, false, 0>(bufF, W1, b1, nullptr, bufB, nullptr, nullptr, 0, node0, t);
    __syncthreads();
    gemm32<false, true,  true, false, 0>(bufB, W2, b2, nullptr, bufF, nullptr, nullptr, 0, node0, t);
    __syncthreads();
    gemm32<false, true,  true, true,  0>(bufF, W3, b3, enc, bufB, nullptr, nullptr, 0, node0, t);
    __syncthreads();
    gemm32<false, false, false, false, 2>(bufB, Wk, nullptr, nullptr, nullptr, nullptr, kv, 0, node0, t);
    gemm32<false, false, false, false, 2>(bufB, Wv, nullptr, nullptr, nullptr, nullptr, kv, 128, node0, t);
}

// qext[n][h*48 + x] = sum_a q[n][h*16+a] * Wk[(128+x)*128 + h*16+a], x in [0,48).
// Wk_ds staged in LDS once per 32 nodes (kills 400MB of per-node L2 reads).
__global__ __launch_bounds__(256) void phaseQ_kernel(
    const float* __restrict__ qout, const float* __restrict__ Wk,
    float* __restrict__ qext)
{
    __shared__ __align__(16) float qt[TM * LDA];
    __shared__ __align__(16) float wk[48 * 128];
    const int t = threadIdx.x;
    const int node0 = blockIdx.x * TM;

#pragma unroll
    for (int r = 0; r < 4; ++r) {
        int fid = t + 256 * r;
        int row = fid >> 5, c4 = (fid & 31) * 4;
        *(float4*)&qt[row * LDA + c4] =
            *(const float4*)&qout[(size_t)(node0 + row) * 128 + c4];
    }
#pragma unroll
    for (int r = 0; r < 6; ++r) {
        int fid = t + 256 * r;
        *(float4*)&wk[fid * 4] = *(const float4*)&Wk[128 * 128 + fid * 4];
    }
    __syncthreads();

    const int m = t >> 3, h = t & 7;
    float q[16];
#pragma unroll
    for (int j = 0; j < 4; ++j)
        *(float4*)&q[j * 4] = *(const float4*)&qt[m * LDA + h * 16 + j * 4];

    float* dst = &qext[(size_t)(node0 + m) * 384 + h * 48];
#pragma unroll
    for (int x0 = 0; x0 < 48; x0 += 4) {
        float res[4];
#pragma unroll
        for (int xx = 0; xx < 4; ++xx) {
            const float* wr = &wk[(x0 + xx) * 128 + h * 16];
            float s = 0.f;
#pragma unroll
            for (int j = 0; j < 4; ++j) {
                float4 wv = *(const float4*)&wr[j * 4];
                s += q[j*4+0]*wv.x + q[j*4+1]*wv.y + q[j*4+2]*wv.z + q[j*4+3]*wv.w;
            }
            res[xx] = s;
        }
        *(float4*)&dst[x0] = make_float4(res[0], res[1], res[2], res[3]);
    }
}

// One node per block. Single gather burst (msgk->regs, msgv->LDS, bf16),
// logits + 32-lane shfl softmax, then o / wdist / wseq straight to global.
__global__ __launch_bounds__(256, 6) void attn_kernel(
    const float* __restrict__ qout, const float* __restrict__ qext,
    const ushort* __restrict__ kv, const float* __restrict__ dist,
    const float* __restrict__ seq, const int* __restrict__ idx,
    float* __restrict__ ovec)
{
    __shared__ float dists[32 * 33];
    __shared__ float seqs[32 * 17];
    __shared__ __align__(16) float qs[128];
    __shared__ __align__(16) float qe[384];
    __shared__ float attn_s[256];
    __shared__ __align__(16) ushort kvv[32 * 128];

    const int t = threadIdx.x;
    const int n = blockIdx.x;
    const int h = t >> 5, k = t & 31;

    // ---- gather burst + streaming loads (all issued before one barrier) ----
    int j = idx[n * 32 + k];
    const uint4* mkp = (const uint4*)(kv + (size_t)j * 256 + h * 16);
    uint4 mk0 = mkp[0], mk1 = mkp[1];

    {   // stage msgv half to LDS: 32 rows x 256B, 8 threads/row
        int r = t >> 3, cc = t & 7;
        int j2 = idx[n * 32 + r];
        const uint4* vp = (const uint4*)(kv + (size_t)j2 * 256 + 128 + cc * 16);
        uint4 v0 = vp[0], v1 = vp[1];
        *(uint4*)&kvv[r * 128 + cc * 16] = v0;
        *(uint4*)&kvv[r * 128 + cc * 16 + 8] = v1;
    }
    {
        float4 v = *(const float4*)&dist[(size_t)n * 1024 + t * 4];
        int kk = t >> 3, d0 = (t & 7) * 4;
        dists[kk * 33 + d0 + 0] = v.x; dists[kk * 33 + d0 + 1] = v.y;
        dists[kk * 33 + d0 + 2] = v.z; dists[kk * 33 + d0 + 3] = v.w;
    }
    if (t < 128) {
        float4 v = *(const float4*)&seq[(size_t)n * 512 + t * 4];
        int kk = t >> 2, s0 = (t & 3) * 4;
        seqs[kk * 17 + s0 + 0] = v.x; seqs[kk * 17 + s0 + 1] = v.y;
        seqs[kk * 17 + s0 + 2] = v.z; seqs[kk * 17 + s0 + 3] = v.w;
    }
    if (t < 32)  *(float4*)&qs[t * 4] = *(const float4*)&qout[(size_t)n * 128 + t * 4];
    if (t < 96)  *(float4*)&qe[t * 4] = *(const float4*)&qext[(size_t)n * 384 + t * 4];
    __syncthreads();

    // ---- logits + softmax over K (32 lanes = one head) ----
    {
        const float* qh = &qs[h * 16];
        float lg =
            qh[0]  * bflo(mk0.x) + qh[1]  * bfhi(mk0.x) +
            qh[2]  * bflo(mk0.y) + qh[3]  * bfhi(mk0.y) +
            qh[4]  * bflo(mk0.z) + qh[5]  * bfhi(mk0.z) +
            qh[6]  * bflo(mk0.w) + qh[7]  * bfhi(mk0.w) +
            qh[8]  * bflo(mk1.x) + qh[9]  * bfhi(mk1.x) +
            qh[10] * bflo(mk1.y) + qh[11] * bfhi(mk1.y) +
            qh[12] * bflo(mk1.z) + qh[13] * bfhi(mk1.z) +
            qh[14] * bflo(mk1.w) + qh[15] * bfhi(mk1.w);
        const float* qeh = &qe[h * 48];
#pragma unroll
        for (int d = 0; d < 32; ++d) lg += dists[k * 33 + d] * qeh[d];
#pragma unroll
        for (int s = 0; s < 16; ++s) lg += seqs[k * 17 + s] * qeh[32 + s];
        lg *= 0.25f;   // 1/sqrt(ADIM=16)
        float mx = lg;
#pragma unroll
        for (int off = 16; off; off >>= 1) mx = fmaxf(mx, __shfl_xor(mx, off));
        float e = __expf(lg - mx);
        float sum = e;
#pragma unroll
        for (int off = 16; off; off >>= 1) sum += __shfl_xor(sum, off);
        attn_s[t] = e / sum;
    }
    __syncthreads();

    // ---- accumulate o / wdist / wseq -> ovec[n][512] = [o | wd | ws] ----
    float* od = &ovec[(size_t)n * 512];
    {
        float wd = 0.f;
#pragma unroll 8
        for (int kk = 0; kk < 32; ++kk) wd += attn_s[h * 32 + kk] * dists[kk * 33 + k];
        od[128 + t] = wd;   // index h*32+d == t
    }
    if (t < 128) {
        const int h2 = t >> 4, s = t & 15;
        float o = 0.f, ws = 0.f;
#pragma unroll 8
        for (int kk = 0; kk < 32; ++kk) {
            float a = attn_s[h2 * 32 + kk];
            o  += a * __uint_as_float((uint)kvv[kk * 128 + t] << 16);
            ws += a * seqs[kk * 17 + s];
        }
        od[t] = o;
        od[384 + t] = ws;   // index h*16+s == t
    }
}

// out = features + ovec @ BigW + cvec   (K = 512, chunked through LDS)
__global__ __launch_bounds__(256) void final_kernel(
    const float* __restrict__ ovec, const float* __restrict__ BigW,
    const float* __restrict__ cvec, const float* __restrict__ features,
    float* __restrict__ out)
{
    __shared__ __align__(16) float bufA[TM * LDA];
    const int t = threadIdx.x;
    const int node0 = blockIdx.x * TM;
    const int m0 = (t >> 5) * 4;
    const int c0 = (t & 31) * 4;
    float acc[4][4];
#pragma unroll
    for (int mm = 0; mm < 4; ++mm)
#pragma unroll
        for (int cc = 0; cc < 4; ++cc) acc[mm][cc] = 0.f;

    for (int ck = 0; ck < 4; ++ck) {
        __syncthreads();
#pragma unroll
        for (int r = 0; r < 4; ++r) {
            int fid = t + 256 * r;
            int row = fid >> 5, c4 = (fid & 31) * 4;
            *(float4*)&bufA[row * LDA + c4] =
                *(const float4*)&ovec[(size_t)(node0 + row) * 512 + ck * 128 + c4];
        }
        __syncthreads();
        const float* Wc = BigW + ck * 128 * 128;
#pragma unroll 4
        for (int ic = 0; ic < 32; ++ic) {
            float a[4][4];
#pragma unroll
            for (int mm = 0; mm < 4; ++mm) {
                float4 av = *(const float4*)&bufA[(m0 + mm) * LDA + ic * 4];
                a[mm][0] = av.x; a[mm][1] = av.y; a[mm][2] = av.z; a[mm][3] = av.w;
            }
            float w[4][4];
#pragma unroll
            for (int ii = 0; ii < 4; ++ii) {
                float4 wv = *(const float4*)&Wc[(ic * 4 + ii) * 128 + c0];
                w[ii][0] = wv.x; w[ii][1] = wv.y; w[ii][2] = wv.z; w[ii][3] = wv.w;
            }
#pragma unroll
            for (int mm = 0; mm < 4; ++mm)
#pragma unroll
                for (int ii = 0; ii < 4; ++ii) {
                    float av = a[mm][ii];
#pragma unroll
                    for (int cc = 0; cc < 4; ++cc)
                        acc[mm][cc] = fmaf(av, w[ii][cc], acc[mm][cc]);
                }
        }
    }
    float4 cv = *(const float4*)&cvec[c0];
#pragma unroll
    for (int mm = 0; mm < 4; ++mm) {
        float4 f = *(const float4*)&features[(size_t)(node0 + m0 + mm) * 128 + c0];
        *(float4*)&out[(size_t)(node0 + m0 + mm) * 128 + c0] =
            make_float4(acc[mm][0] + f.x + cv.x, acc[mm][1] + f.y + cv.y,
                        acc[mm][2] + f.z + cv.z, acc[mm][3] + f.w + cv.w);
    }
}

// BigW[512][128]: rows 0-127 = Wo; 128+h*32+d = Wv_dist(d,h)@Wo_h; 384+h*16+s = Wv_seq(s,h)@Wo_h.
// cvec = bv@Wo + bo.
__global__ void wprep_kernel(
    const float* __restrict__ Wv, const float* __restrict__ Wo,
    const float* __restrict__ bv, const float* __restrict__ bo,
    float* __restrict__ BigW, float* __restrict__ cvec)
{
    const int r = blockIdx.x;   // 0..511
    const int c = threadIdx.x;  // 0..127
    float s = 0.f;
    if (r < 128) {
        s = Wo[r * 128 + c];
    } else if (r < 384) {
        int x = r - 128; int hh = x >> 5, d = x & 31;
#pragma unroll
        for (int a = 0; a < 16; ++a)
            s += Wv[(128 + d) * 128 + hh * 16 + a] * Wo[(hh * 16 + a) * 128 + c];
    } else {
        int x = r - 384; int hh = x >> 4, ss = x & 15;
#pragma unroll
        for (int a = 0; a < 16; ++a)
            s += Wv[(160 + ss) * 128 + hh * 16 + a] * Wo[(hh * 16 + a) * 128 + c];
    }
    BigW[r * 128 + c] = s;
    if (r == 0) {
        float cv = bo[c];
        for (int jj = 0; jj < 128; ++jj) cv += bv[jj] * Wo[jj * 128 + c];
        cvec[c] = cv;
    }
}

extern "C" void kernel_launch(void* const* d_in, const int* in_sizes, int n_in,
                              void* d_out, int out_size, void* d_ws, size_t ws_size,
                              hipStream_t stream)
{
    const float* features = (const float*)d_in[0];
    const float* dist     = (const float*)d_in[1];
    const float* seq      = (const float*)d_in[2];
    const float* enc      = (const float*)d_in[3];
    const int*   idx      = (const int*)d_in[4];
    const float* W1 = (const float*)d_in[5];
    const float* b1 = (const float*)d_in[6];
    const float* W2 = (const float*)d_in[7];
    const float* b2 = (const float*)d_in[8];
    const float* W3 = (const float*)d_in[9];
    const float* b3 = (const float*)d_in[10];
    const float* Wq = (const float*)d_in[11];
    const float* bq = (const float*)d_in[12];
    const float* Wk = (const float*)d_in[13];
    // d_in[14] = bk: dropped (softmax-invariant)
    const float* Wv = (const float*)d_in[15];
    const float* bv = (const float*)d_in[16];
    const float* Wo = (const float*)d_in[17];
    const float* bo = (const float*)d_in[18];
    float* out = (float*)d_out;

    char* ws = (char*)d_ws;
    ushort* kv   = (ushort*)ws;                               // 8 MB
    float*  qout = (float*)(ws + ((size_t)8  << 20));         // 8 MB
    float*  qext = (float*)(ws + ((size_t)16 << 20));         // 24 MB
    float*  ovec = (float*)(ws + ((size_t)40 << 20));         // 32 MB
    float*  BigW = (float*)(ws + ((size_t)72 << 20));         // 256 KB
    float*  cvec = (float*)(ws + ((size_t)72 << 20) + 512 * 128 * 4);

    wprep_kernel<<<512, 128, 0, stream>>>(Wv, Wo, bv, bo, BigW, cvec);
    phaseA_kernel<<<NN / TM, 256, 0, stream>>>(
        features, enc, W1, b1, W2, b2, W3, b3, Wq, bq, Wk, Wv, qout, kv);
    phaseQ_kernel<<<NN / TM, 256, 0, stream>>>(qout, Wk, qext);
    attn_kernel<<<NN, 256, 0, stream>>>(qout, qext, kv, dist, seq, idx, ovec);
    final_kernel<<<NN / TM, 256, 0, stream>>>(ovec, BigW, cvec, features, out);
}

// Round 6
// 298.311 us; speedup vs baseline: 1.4429x; 1.2546x over previous
//
#include <hip/hip_runtime.h>
#include <hip/hip_fp16.h>
#include <math.h>

#define NN 16384
#define TM 32
#define LDA 132   // f32 LDS row stride (128 + 4 pad)
#define LDH 136   // f16 LDS row stride (128 + 8 pad, keeps 16B alignment: 136*2=272=16*17)

typedef unsigned int uint;
typedef unsigned short ushort;
typedef _Float16 half8 __attribute__((ext_vector_type(8)));
typedef float floatx4 __attribute__((ext_vector_type(4)));

__device__ __forceinline__ uint pack2h(float a, float b) {
    _Float16 ha = (_Float16)a, hb = (_Float16)b;
    ushort ua = *(ushort*)&ha, ub = *(ushort*)&hb;
    return (uint)ua | ((uint)ub << 16);
}
__device__ __forceinline__ float2 h2f2(uint u) {
    __half2 h = *(__half2*)&u;
    return __half22float2(h);
}

// ================= phaseA: MFMA f16 fused 6-GEMM chain =================
// Tile: 32 nodes x 128 cols, 4 waves. Wave w: row-tile (w&1), col-tiles (w>>1)*4..+3.
// A-frag: A[m=lane&15][k=quad*8+j]   B-frag: B[k=quad*8+j][n=lane&15]
// C/D: col=lane&15, row=quad*4+reg (m89-verified).

struct Acc4 { floatx4 a[4]; };

template<bool RELUA>
__device__ __forceinline__ Acc4 mfma_gemm(const ushort* Ab, const half8* wp, int lane, int w)
{
    const int m  = (w & 1) * 16 + (lane & 15);
    const int kq = (lane >> 4) * 8;
    const int cg = w >> 1;
    half8 afr[4];
#pragma unroll
    for (int ks = 0; ks < 4; ++ks) {
        afr[ks] = *(const half8*)&Ab[m * LDH + ks * 32 + kq];
        if (RELUA) {
#pragma unroll
            for (int j = 0; j < 8; ++j)
                afr[ks][j] = afr[ks][j] > (_Float16)0.f ? afr[ks][j] : (_Float16)0.f;
        }
    }
    Acc4 r;
#pragma unroll
    for (int ct = 0; ct < 4; ++ct) {
        const int CT = cg * 4 + ct;
        floatx4 acc = {0.f, 0.f, 0.f, 0.f};
#pragma unroll
        for (int ks = 0; ks < 4; ++ks) {
            half8 bfr = wp[(CT * 4 + ks) * 64 + lane];
            acc = __builtin_amdgcn_mfma_f32_16x16x32_f16(afr[ks], bfr, acc, 0, 0, 0);
        }
        r.a[ct] = acc;
    }
    return r;
}

template<bool HAS_BIAS, bool RELU, bool HAS_ENC, bool F16OUT>
__device__ __forceinline__ void epilogue(const Acc4& ac, const float* __restrict__ bias,
    const float* __restrict__ enc, ushort* dst16, float* dst32,
    int node0, int lane, int w)
{
    const int row0 = (w & 1) * 16 + ((lane >> 4) << 2);
    const int cg = w >> 1;
#pragma unroll
    for (int ct = 0; ct < 4; ++ct) {
        const int col = (cg * 4 + ct) * 16 + (lane & 15);
        float bb = HAS_BIAS ? bias[col] : 0.f;
#pragma unroll
        for (int r = 0; r < 4; ++r) {
            float x = ac.a[ct][r] + bb;
            if (RELU) x = fmaxf(x, 0.f);
            if (HAS_ENC) x += enc[(size_t)(node0 + row0 + r) * 128 + col];
            if (F16OUT) {
                _Float16 h = (_Float16)x;
                dst16[(row0 + r) * LDH + col] = *(ushort*)&h;
            } else {
                dst32[(row0 + r) * LDA + col] = x;
            }
        }
    }
}

__global__ __launch_bounds__(256) void phaseA_kernel(
    const float* __restrict__ features, const float* __restrict__ enc,
    const float* __restrict__ b1, const float* __restrict__ b2,
    const float* __restrict__ b3, const float* __restrict__ bq,
    const ushort* __restrict__ wpack,
    float* __restrict__ qout, ushort* __restrict__ kv)
{
    __shared__ __align__(16) ushort bufA[TM * LDH];
    __shared__ __align__(16) ushort bufB[TM * LDH];
    __shared__ __align__(16) float  qstage[TM * LDA];
    ushort* vstage = (ushort*)qstage;

    const int t = threadIdx.x;
    const int lane = t & 63, w = t >> 6;
    const int node0 = blockIdx.x * TM;

    const half8* wpQ = (const half8*)(wpack + 0 * 16384);
    const half8* wp1 = (const half8*)(wpack + 1 * 16384);
    const half8* wp2 = (const half8*)(wpack + 2 * 16384);
    const half8* wp3 = (const half8*)(wpack + 3 * 16384);
    const half8* wpK = (const half8*)(wpack + 4 * 16384);
    const half8* wpV = (const half8*)(wpack + 5 * 16384);

    // stage features -> f16 LDS
#pragma unroll
    for (int r = 0; r < 4; ++r) {
        int fid = t + 256 * r;
        int row = fid >> 5, c4 = (fid & 31) * 4;
        float4 v = *(const float4*)&features[(size_t)(node0 + row) * 128 + c4];
        uint2 h = make_uint2(pack2h(v.x, v.y), pack2h(v.z, v.w));
        *(uint2*)&bufA[row * LDH + c4] = h;
    }
    __syncthreads();

    Acc4 aQ = mfma_gemm<false>(bufA, wpQ, lane, w);          // q = F@Wq
    Acc4 a1 = mfma_gemm<true >(bufA, wp1, lane, w);          // relu(F)@W1
    epilogue<true, false, false, false>(aQ, bq, nullptr, nullptr, qstage, node0, lane, w);
    epilogue<true, true,  false, true >(a1, b1, nullptr, bufB, nullptr, node0, lane, w);
    __syncthreads();

#pragma unroll
    for (int r = 0; r < 4; ++r) {   // qstage -> qout (coalesced)
        int fid = t + 256 * r;
        int row = fid >> 5, c4 = (fid & 31) * 4;
        *(float4*)&qout[(size_t)(node0 + row) * 128 + c4] =
            *(const float4*)&qstage[row * LDA + c4];
    }
    Acc4 a2 = mfma_gemm<false>(bufB, wp2, lane, w);          // h1@W2
    epilogue<true, true, false, true>(a2, b2, nullptr, bufA, nullptr, node0, lane, w);
    __syncthreads();

    Acc4 a3 = mfma_gemm<false>(bufA, wp3, lane, w);          // h2@W3
    epilogue<true, true, true, true>(a3, b3, enc, bufB, nullptr, node0, lane, w);  // msg
    __syncthreads();

    Acc4 aK = mfma_gemm<false>(bufB, wpK, lane, w);          // msg@Wk[:128]
    Acc4 aV = mfma_gemm<false>(bufB, wpV, lane, w);          // msg@Wv[:128]
    epilogue<false, false, false, true>(aK, nullptr, nullptr, bufA,   nullptr, node0, lane, w);
    epilogue<false, false, false, true>(aV, nullptr, nullptr, vstage, nullptr, node0, lane, w);
    __syncthreads();

    // kv store. Each half is 32 rows x 128 ushorts; uint4 = 8 ushorts, so two
    // uint4 per half per thread (R4 bug: one -> poison in odd sub-blocks).
    {
        int row = t >> 3, c16 = (t & 7) * 16;
        size_t kbase = (size_t)(node0 + row) * 256;
        *(uint4*)&kv[kbase + c16]           = *(const uint4*)&bufA[row * LDH + c16];
        *(uint4*)&kv[kbase + c16 + 8]       = *(const uint4*)&bufA[row * LDH + c16 + 8];
        *(uint4*)&kv[kbase + 128 + c16]     = *(const uint4*)&vstage[row * LDH + c16];
        *(uint4*)&kv[kbase + 128 + c16 + 8] = *(const uint4*)&vstage[row * LDH + c16 + 8];
    }
}

// wpack[g][CT][ks][lane][j] = f16 W_g[ks*32 + (lane>>4)*8 + j][CT*16 + (lane&15)]
__global__ void wpack_kernel(
    const float* __restrict__ W1, const float* __restrict__ W2,
    const float* __restrict__ W3, const float* __restrict__ Wq,
    const float* __restrict__ Wk, const float* __restrict__ Wv,
    ushort* __restrict__ wpack)
{
    const int g = blockIdx.x >> 5;
    const int rem = blockIdx.x & 31;
    const int CT = rem >> 2, ks = rem & 3;
    const int lane = threadIdx.x;
    const float* W = (g == 0) ? Wq : (g == 1) ? W1 : (g == 2) ? W2
                   : (g == 3) ? W3 : (g == 4) ? Wk : Wv;
    const int n = CT * 16 + (lane & 15);
    const int k0 = ks * 32 + (lane >> 4) * 8;
    ushort out[8];
#pragma unroll
    for (int j = 0; j < 8; ++j) {
        _Float16 h = (_Float16)W[(k0 + j) * 128 + n];
        out[j] = *(ushort*)&h;
    }
    *(uint4*)&wpack[(size_t)(((g * 8 + CT) * 4 + ks) * 64 + lane) * 8] = *(uint4*)out;
}

// ================= phaseQ: qext(f16) = per-head q @ Wk_dist/seq =================
__global__ __launch_bounds__(256) void phaseQ_kernel(
    const float* __restrict__ qout, const float* __restrict__ Wk,
    ushort* __restrict__ qext)
{
    __shared__ __align__(16) float qt[TM * LDA];
    __shared__ __align__(16) float wk[48 * 128];
    const int t = threadIdx.x;
    const int node0 = blockIdx.x * TM;

#pragma unroll
    for (int r = 0; r < 4; ++r) {
        int fid = t + 256 * r;
        int row = fid >> 5, c4 = (fid & 31) * 4;
        *(float4*)&qt[row * LDA + c4] =
            *(const float4*)&qout[(size_t)(node0 + row) * 128 + c4];
    }
#pragma unroll
    for (int r = 0; r < 6; ++r) {
        int fid = t + 256 * r;
        *(float4*)&wk[fid * 4] = *(const float4*)&Wk[128 * 128 + fid * 4];
    }
    __syncthreads();

    const int m = t >> 3, h = t & 7;
    float q[16];
#pragma unroll
    for (int j = 0; j < 4; ++j)
        *(float4*)&q[j * 4] = *(const float4*)&qt[m * LDA + h * 16 + j * 4];

    ushort* dst = &qext[(size_t)(node0 + m) * 384 + h * 48];
#pragma unroll
    for (int x0 = 0; x0 < 48; x0 += 8) {
        float res[8];
#pragma unroll
        for (int xx = 0; xx < 8; ++xx) {
            const float* wr = &wk[(x0 + xx) * 128 + h * 16];
            float s = 0.f;
#pragma unroll
            for (int j = 0; j < 4; ++j) {
                float4 wv = *(const float4*)&wr[j * 4];
                s += q[j*4+0]*wv.x + q[j*4+1]*wv.y + q[j*4+2]*wv.z + q[j*4+3]*wv.w;
            }
            res[xx] = s;
        }
        uint4 pk = make_uint4(pack2h(res[0], res[1]), pack2h(res[2], res[3]),
                              pack2h(res[4], res[5]), pack2h(res[6], res[7]));
        *(uint4*)&dst[x0] = pk;
    }
}

// ================= attn: gather + softmax + weighted sums =================
__global__ __launch_bounds__(256, 6) void attn_kernel(
    const float* __restrict__ qout, const ushort* __restrict__ qext,
    const ushort* __restrict__ kv, const float* __restrict__ dist,
    const float* __restrict__ seq, const int* __restrict__ idx,
    float* __restrict__ ovec)
{
    __shared__ float dists[32 * 33];
    __shared__ float seqs[32 * 17];
    __shared__ __align__(16) float qs[128];
    __shared__ __align__(16) float qe[384];
    __shared__ float attn_s[256];
    __shared__ __align__(16) ushort kvv[32 * 128];

    const int t = threadIdx.x;
    const int n = blockIdx.x;
    const int h = t >> 5, k = t & 31;

    int j = idx[n * 32 + k];
    const uint4* mkp = (const uint4*)(kv + (size_t)j * 256 + h * 16);
    uint4 mk0 = mkp[0], mk1 = mkp[1];

    {   // stage msgv half to LDS: 32 rows x 256B, 8 threads/row
        int r = t >> 3, cc = t & 7;
        int j2 = idx[n * 32 + r];
        const uint4* vp = (const uint4*)(kv + (size_t)j2 * 256 + 128 + cc * 16);
        uint4 v0 = vp[0], v1 = vp[1];
        *(uint4*)&kvv[r * 128 + cc * 16] = v0;
        *(uint4*)&kvv[r * 128 + cc * 16 + 8] = v1;
    }
    {
        float4 v = *(const float4*)&dist[(size_t)n * 1024 + t * 4];
        int kk = t >> 3, d0 = (t & 7) * 4;
        dists[kk * 33 + d0 + 0] = v.x; dists[kk * 33 + d0 + 1] = v.y;
        dists[kk * 33 + d0 + 2] = v.z; dists[kk * 33 + d0 + 3] = v.w;
    }
    if (t < 128) {
        float4 v = *(const float4*)&seq[(size_t)n * 512 + t * 4];
        int kk = t >> 2, s0 = (t & 3) * 4;
        seqs[kk * 17 + s0 + 0] = v.x; seqs[kk * 17 + s0 + 1] = v.y;
        seqs[kk * 17 + s0 + 2] = v.z; seqs[kk * 17 + s0 + 3] = v.w;
    }
    if (t < 32)  *(float4*)&qs[t * 4] = *(const float4*)&qout[(size_t)n * 128 + t * 4];
    if (t < 96) {   // unpack f16 qext -> f32 LDS
        uint2 u = *(const uint2*)&qext[(size_t)n * 384 + t * 4];
        float2 a = h2f2(u.x), b = h2f2(u.y);
        qe[t * 4 + 0] = a.x; qe[t * 4 + 1] = a.y;
        qe[t * 4 + 2] = b.x; qe[t * 4 + 3] = b.y;
    }
    __syncthreads();

    {
        const float* qh = &qs[h * 16];
        float2 p;
        float lg = 0.f;
        p = h2f2(mk0.x); lg += qh[0]  * p.x + qh[1]  * p.y;
        p = h2f2(mk0.y); lg += qh[2]  * p.x + qh[3]  * p.y;
        p = h2f2(mk0.z); lg += qh[4]  * p.x + qh[5]  * p.y;
        p = h2f2(mk0.w); lg += qh[6]  * p.x + qh[7]  * p.y;
        p = h2f2(mk1.x); lg += qh[8]  * p.x + qh[9]  * p.y;
        p = h2f2(mk1.y); lg += qh[10] * p.x + qh[11] * p.y;
        p = h2f2(mk1.z); lg += qh[12] * p.x + qh[13] * p.y;
        p = h2f2(mk1.w); lg += qh[14] * p.x + qh[15] * p.y;
        const float* qeh = &qe[h * 48];
#pragma unroll
        for (int d = 0; d < 32; ++d) lg += dists[k * 33 + d] * qeh[d];
#pragma unroll
        for (int s = 0; s < 16; ++s) lg += seqs[k * 17 + s] * qeh[32 + s];
        lg *= 0.25f;   // 1/sqrt(ADIM=16)
        float mx = lg;
#pragma unroll
        for (int off = 16; off; off >>= 1) mx = fmaxf(mx, __shfl_xor(mx, off));
        float e = __expf(lg - mx);
        float sum = e;
#pragma unroll
        for (int off = 16; off; off >>= 1) sum += __shfl_xor(sum, off);
        attn_s[t] = e / sum;
    }
    __syncthreads();

    float* od = &ovec[(size_t)n * 512];
    {
        float wd = 0.f;
#pragma unroll 8
        for (int kk = 0; kk < 32; ++kk) wd += attn_s[h * 32 + kk] * dists[kk * 33 + k];
        od[128 + t] = wd;
    }
    if (t < 128) {
        const int h2 = t >> 4, s = t & 15;
        float o = 0.f, ws = 0.f;
#pragma unroll 8
        for (int kk = 0; kk < 32; ++kk) {
            float a = attn_s[h2 * 32 + kk];
            ushort uv = kvv[kk * 128 + t];
            o  += a * __half2float(*(__half*)&uv);
            ws += a * seqs[kk * 17 + s];
        }
        od[t] = o;
        od[384 + t] = ws;
    }
}

// ================= final: out = features + ovec @ BigW + cvec =================
__global__ __launch_bounds__(256) void final_kernel(
    const float* __restrict__ ovec, const float* __restrict__ BigW,
    const float* __restrict__ cvec, const float* __restrict__ features,
    float* __restrict__ out)
{
    __shared__ __align__(16) float bufA[TM * LDA];
    const int t = threadIdx.x;
    const int node0 = blockIdx.x * TM;
    const int m0 = (t >> 5) * 4;
    const int c0 = (t & 31) * 4;
    float acc[4][4];
#pragma unroll
    for (int mm = 0; mm < 4; ++mm)
#pragma unroll
        for (int cc = 0; cc < 4; ++cc) acc[mm][cc] = 0.f;

    for (int ck = 0; ck < 4; ++ck) {
        __syncthreads();
#pragma unroll
        for (int r = 0; r < 4; ++r) {
            int fid = t + 256 * r;
            int row = fid >> 5, c4 = (fid & 31) * 4;
            *(float4*)&bufA[row * LDA + c4] =
                *(const float4*)&ovec[(size_t)(node0 + row) * 512 + ck * 128 + c4];
        }
        __syncthreads();
        const float* Wc = BigW + ck * 128 * 128;
#pragma unroll 4
        for (int ic = 0; ic < 32; ++ic) {
            float a[4][4];
#pragma unroll
            for (int mm = 0; mm < 4; ++mm) {
                float4 av = *(const float4*)&bufA[(m0 + mm) * LDA + ic * 4];
                a[mm][0] = av.x; a[mm][1] = av.y; a[mm][2] = av.z; a[mm][3] = av.w;
            }
            float w[4][4];
#pragma unroll
            for (int ii = 0; ii < 4; ++ii) {
                float4 wv = *(const float4*)&Wc[(ic * 4 + ii) * 128 + c0];
                w[ii][0] = wv.x; w[ii][1] = wv.y; w[ii][2] = wv.z; w[ii][3] = wv.w;
            }
#pragma unroll
            for (int mm = 0; mm < 4; ++mm)
#pragma unroll
                for (int ii = 0; ii < 4; ++ii) {
                    float av = a[mm][ii];
#pragma unroll
                    for (int cc = 0; cc < 4; ++cc)
                        acc[mm][cc] = fmaf(av, w[ii][cc], acc[mm][cc]);
                }
        }
    }
    float4 cv = *(const float4*)&cvec[c0];
#pragma unroll
    for (int mm = 0; mm < 4; ++mm) {
        float4 f = *(const float4*)&features[(size_t)(node0 + m0 + mm) * 128 + c0];
        *(float4*)&out[(size_t)(node0 + m0 + mm) * 128 + c0] =
            make_float4(acc[mm][0] + f.x + cv.x, acc[mm][1] + f.y + cv.y,
                        acc[mm][2] + f.z + cv.z, acc[mm][3] + f.w + cv.w);
    }
}

// BigW[512][128]: rows 0-127 = Wo; 128+h*32+d = Wv_dist(d,h)@Wo_h; 384+h*16+s = Wv_seq(s,h)@Wo_h.
__global__ void wprep_kernel(
    const float* __restrict__ Wv, const float* __restrict__ Wo,
    const float* __restrict__ bv, const float* __restrict__ bo,
    float* __restrict__ BigW, float* __restrict__ cvec)
{
    const int r = blockIdx.x;   // 0..511
    const int c = threadIdx.x;  // 0..127
    float s = 0.f;
    if (r < 128) {
        s = Wo[r * 128 + c];
    } else if (r < 384) {
        int x = r - 128; int hh = x >> 5, d = x & 31;
#pragma unroll
        for (int a = 0; a < 16; ++a)
            s += Wv[(128 + d) * 128 + hh * 16 + a] * Wo[(hh * 16 + a) * 128 + c];
    } else {
        int x = r - 384; int hh = x >> 4, ss = x & 15;
#pragma unroll
        for (int a = 0; a < 16; ++a)
            s += Wv[(160 + ss) * 128 + hh * 16 + a] * Wo[(hh * 16 + a) * 128 + c];
    }
    BigW[r * 128 + c] = s;
    if (r == 0) {
        float cv = bo[c];
        for (int jj = 0; jj < 128; ++jj) cv += bv[jj] * Wo[jj * 128 + c];
        cvec[c] = cv;
    }
}

extern "C" void kernel_launch(void* const* d_in, const int* in_sizes, int n_in,
                              void* d_out, int out_size, void* d_ws, size_t ws_size,
                              hipStream_t stream)
{
    const float* features = (const float*)d_in[0];
    const float* dist     = (const float*)d_in[1];
    const float* seq      = (const float*)d_in[2];
    const float* enc      = (const float*)d_in[3];
    const int*   idx      = (const int*)d_in[4];
    const float* W1 = (const float*)d_in[5];
    const float* b1 = (const float*)d_in[6];
    const float* W2 = (const float*)d_in[7];
    const float* b2 = (const float*)d_in[8];
    const float* W3 = (const float*)d_in[9];
    const float* b3 = (const float*)d_in[10];
    const float* Wq = (const float*)d_in[11];
    const float* bq = (const float*)d_in[12];
    const float* Wk = (const float*)d_in[13];
    // d_in[14] = bk: dropped (softmax-invariant)
    const float* Wv = (const float*)d_in[15];
    const float* bv = (const float*)d_in[16];
    const float* Wo = (const float*)d_in[17];
    const float* bo = (const float*)d_in[18];
    float* out = (float*)d_out;

    // Compact workspace layout — total ~60.45 MB, well under the R2-proven
    // 72.25 MB bound (R5 bug: wpack at 73 MB offset wrote past ws_size and
    // corrupted harness memory -> consistent post-timing divergence).
    char* ws = (char*)d_ws;
    ushort* kv    = (ushort*)ws;                              //  0 MB: 8 MB (f16)
    float*  qout  = (float*)(ws + ((size_t)8  << 20));        //  8 MB: 8 MB f32
    ushort* qext  = (ushort*)(ws + ((size_t)16 << 20));       // 16 MB: 12 MB f16
    float*  ovec  = (float*)(ws + ((size_t)28 << 20));        // 28 MB: 32 MB f32
    float*  BigW  = (float*)(ws + ((size_t)60 << 20));        // 60 MB: 256 KB
    float*  cvec  = (float*)(ws + ((size_t)60 << 20) + 262144);          // 512 B
    ushort* wpack = (ushort*)(ws + ((size_t)60 << 20) + 262144 + 512);   // 192 KB

    wprep_kernel<<<512, 128, 0, stream>>>(Wv, Wo, bv, bo, BigW, cvec);
    wpack_kernel<<<192, 64, 0, stream>>>(W1, W2, W3, Wq, Wk, Wv, wpack);
    phaseA_kernel<<<NN / TM, 256, 0, stream>>>(
        features, enc, b1, b2, b3, bq, wpack, qout, kv);
    phaseQ_kernel<<<NN / TM, 256, 0, stream>>>(qout, Wk, qext);
    attn_kernel<<<NN, 256, 0, stream>>>(qout, qext, kv, dist, seq, idx, ovec);
    final_kernel<<<NN / TM, 256, 0, stream>>>(ovec, BigW, cvec, features, out);
}

// Round 7
// 271.097 us; speedup vs baseline: 1.5878x; 1.1004x over previous
//
#include <hip/hip_runtime.h>
#include <hip/hip_fp16.h>
#include <math.h>

#define NN 16384
#define TM 32
#define LDA 132   // f32 LDS row stride (128 + 4 pad)
#define LDH 136   // f16 LDS row stride (128 + 8 pad, keeps 16B alignment)
#define LDD 36    // dists row stride (f32): 16B-aligned rows, conflict-free columns
#define LDS_ 20   // seqs row stride (f32)

typedef unsigned int uint;
typedef unsigned short ushort;
typedef _Float16 half8 __attribute__((ext_vector_type(8)));
typedef float floatx4 __attribute__((ext_vector_type(4)));

__device__ __forceinline__ uint pack2h(float a, float b) {
    _Float16 ha = (_Float16)a, hb = (_Float16)b;
    ushort ua = *(ushort*)&ha, ub = *(ushort*)&hb;
    return (uint)ua | ((uint)ub << 16);
}
__device__ __forceinline__ float2 h2f2(uint u) {
    __half2 h = *(__half2*)&u;
    return __half22float2(h);
}

// ================= phaseA: MFMA f16 fused 6-GEMM chain + qext =================
// Tile: 32 nodes x 128 cols, 4 waves. Wave w: row-tile (w&1), col-tiles (w>>1)*4..+3.
// A-frag: A[m=lane&15][k=quad*8+j]   B-frag: B[k=quad*8+j][n=lane&15]
// C/D: col=lane&15, row=quad*4+reg (m89-verified).

struct Acc4 { floatx4 a[4]; };

template<bool RELUA>
__device__ __forceinline__ Acc4 mfma_gemm(const ushort* Ab, const half8* wp, int lane, int w)
{
    const int m  = (w & 1) * 16 + (lane & 15);
    const int kq = (lane >> 4) * 8;
    const int cg = w >> 1;
    half8 afr[4];
#pragma unroll
    for (int ks = 0; ks < 4; ++ks) {
        afr[ks] = *(const half8*)&Ab[m * LDH + ks * 32 + kq];
        if (RELUA) {
#pragma unroll
            for (int j = 0; j < 8; ++j)
                afr[ks][j] = afr[ks][j] > (_Float16)0.f ? afr[ks][j] : (_Float16)0.f;
        }
    }
    Acc4 r;
#pragma unroll
    for (int ct = 0; ct < 4; ++ct) {
        const int CT = cg * 4 + ct;
        floatx4 acc = {0.f, 0.f, 0.f, 0.f};
#pragma unroll
        for (int ks = 0; ks < 4; ++ks) {
            half8 bfr = wp[(CT * 4 + ks) * 64 + lane];
            acc = __builtin_amdgcn_mfma_f32_16x16x32_f16(afr[ks], bfr, acc, 0, 0, 0);
        }
        r.a[ct] = acc;
    }
    return r;
}

template<bool HAS_BIAS, bool RELU, bool HAS_ENC, bool F16OUT>
__device__ __forceinline__ void epilogue(const Acc4& ac, const float* __restrict__ bias,
    const float* __restrict__ enc, ushort* dst16, float* dst32,
    int node0, int lane, int w)
{
    const int row0 = (w & 1) * 16 + ((lane >> 4) << 2);
    const int cg = w >> 1;
#pragma unroll
    for (int ct = 0; ct < 4; ++ct) {
        const int col = (cg * 4 + ct) * 16 + (lane & 15);
        float bb = HAS_BIAS ? bias[col] : 0.f;
#pragma unroll
        for (int r = 0; r < 4; ++r) {
            float x = ac.a[ct][r] + bb;
            if (RELU) x = fmaxf(x, 0.f);
            if (HAS_ENC) x += enc[(size_t)(node0 + row0 + r) * 128 + col];
            if (F16OUT) {
                _Float16 h = (_Float16)x;
                dst16[(row0 + r) * LDH + col] = *(ushort*)&h;
            } else {
                dst32[(row0 + r) * LDA + col] = x;
            }
        }
    }
}

__global__ __launch_bounds__(256) void phaseA_kernel(
    const float* __restrict__ features, const float* __restrict__ enc,
    const float* __restrict__ b1, const float* __restrict__ b2,
    const float* __restrict__ b3, const float* __restrict__ bq,
    const float* __restrict__ Wk, const ushort* __restrict__ wpack,
    ushort* __restrict__ qext, ushort* __restrict__ kv)
{
    __shared__ __align__(16) ushort bufA[TM * LDH];
    __shared__ __align__(16) ushort bufB[TM * LDH];
    __shared__ __align__(16) float  qstage[TM * LDA];
    __shared__ __align__(16) float  wk[48 * 128];
    ushort* vstage = (ushort*)qstage;

    const int t = threadIdx.x;
    const int lane = t & 63, w = t >> 6;
    const int node0 = blockIdx.x * TM;

    const half8* wpQ = (const half8*)(wpack + 0 * 16384);
    const half8* wp1 = (const half8*)(wpack + 1 * 16384);
    const half8* wp2 = (const half8*)(wpack + 2 * 16384);
    const half8* wp3 = (const half8*)(wpack + 3 * 16384);
    const half8* wpK = (const half8*)(wpack + 4 * 16384);
    const half8* wpV = (const half8*)(wpack + 5 * 16384);

    // stage features -> f16 LDS; Wk_dist/seq -> f32 LDS (for fused qext)
#pragma unroll
    for (int r = 0; r < 4; ++r) {
        int fid = t + 256 * r;
        int row = fid >> 5, c4 = (fid & 31) * 4;
        float4 v = *(const float4*)&features[(size_t)(node0 + row) * 128 + c4];
        uint2 h = make_uint2(pack2h(v.x, v.y), pack2h(v.z, v.w));
        *(uint2*)&bufA[row * LDH + c4] = h;
    }
#pragma unroll
    for (int r = 0; r < 6; ++r) {
        int fid = t + 256 * r;
        *(float4*)&wk[fid * 4] = *(const float4*)&Wk[128 * 128 + fid * 4];
    }
    __syncthreads();

    Acc4 aQ = mfma_gemm<false>(bufA, wpQ, lane, w);          // q = F@Wq
    Acc4 a1 = mfma_gemm<true >(bufA, wp1, lane, w);          // relu(F)@W1
    epilogue<true, false, false, false>(aQ, bq, nullptr, nullptr, qstage, node0, lane, w);
    epilogue<true, true,  false, true >(a1, b1, nullptr, bufB, nullptr, node0, lane, w);
    __syncthreads();

    Acc4 a2 = mfma_gemm<false>(bufB, wp2, lane, w);          // h1@W2

    // ---- fused qext: per (node m, head hh): 48 ext dots + q copy, all f16 out ----
    {
        const int m = t >> 3, hh = t & 7;
        float q[16];
#pragma unroll
        for (int jj = 0; jj < 4; ++jj)
            *(float4*)&q[jj * 4] = *(const float4*)&qstage[m * LDA + hh * 16 + jj * 4];
        ushort* dst = &qext[(size_t)(node0 + m) * 512 + hh * 64];
#pragma unroll
        for (int x0 = 0; x0 < 48; x0 += 8) {
            float res[8];
#pragma unroll
            for (int xx = 0; xx < 8; ++xx) {
                const float* wr = &wk[(x0 + xx) * 128 + hh * 16];
                float s = 0.f;
#pragma unroll
                for (int jj = 0; jj < 4; ++jj) {
                    float4 wv = *(const float4*)&wr[jj * 4];
                    s += q[jj*4+0]*wv.x + q[jj*4+1]*wv.y + q[jj*4+2]*wv.z + q[jj*4+3]*wv.w;
                }
                res[xx] = s;
            }
            *(uint4*)&dst[x0] = make_uint4(pack2h(res[0], res[1]), pack2h(res[2], res[3]),
                                           pack2h(res[4], res[5]), pack2h(res[6], res[7]));
        }
        *(uint4*)&dst[48] = make_uint4(pack2h(q[0], q[1]),  pack2h(q[2], q[3]),
                                       pack2h(q[4], q[5]),  pack2h(q[6], q[7]));
        *(uint4*)&dst[56] = make_uint4(pack2h(q[8], q[9]),  pack2h(q[10], q[11]),
                                       pack2h(q[12], q[13]), pack2h(q[14], q[15]));
    }
    epilogue<true, true, false, true>(a2, b2, nullptr, bufA, nullptr, node0, lane, w);
    __syncthreads();

    Acc4 a3 = mfma_gemm<false>(bufA, wp3, lane, w);          // h2@W3
    epilogue<true, true, true, true>(a3, b3, enc, bufB, nullptr, node0, lane, w);  // msg
    __syncthreads();

    Acc4 aK = mfma_gemm<false>(bufB, wpK, lane, w);          // msg@Wk[:128]
    Acc4 aV = mfma_gemm<false>(bufB, wpV, lane, w);          // msg@Wv[:128]
    epilogue<false, false, false, true>(aK, nullptr, nullptr, bufA,   nullptr, node0, lane, w);
    epilogue<false, false, false, true>(aV, nullptr, nullptr, vstage, nullptr, node0, lane, w);
    __syncthreads();

    // kv store: two uint4 (8 ushorts each) per half per thread.
    {
        int row = t >> 3, c16 = (t & 7) * 16;
        size_t kbase = (size_t)(node0 + row) * 256;
        *(uint4*)&kv[kbase + c16]           = *(const uint4*)&bufA[row * LDH + c16];
        *(uint4*)&kv[kbase + c16 + 8]       = *(const uint4*)&bufA[row * LDH + c16 + 8];
        *(uint4*)&kv[kbase + 128 + c16]     = *(const uint4*)&vstage[row * LDH + c16];
        *(uint4*)&kv[kbase + 128 + c16 + 8] = *(const uint4*)&vstage[row * LDH + c16 + 8];
    }
}

// wpack[g][CT][ks][lane][j] = f16 W_g[ks*32 + (lane>>4)*8 + j][CT*16 + (lane&15)]
__global__ void wpack_kernel(
    const float* __restrict__ W1, const float* __restrict__ W2,
    const float* __restrict__ W3, const float* __restrict__ Wq,
    const float* __restrict__ Wk, const float* __restrict__ Wv,
    ushort* __restrict__ wpack)
{
    const int g = blockIdx.x >> 5;
    const int rem = blockIdx.x & 31;
    const int CT = rem >> 2, ks = rem & 3;
    const int lane = threadIdx.x;
    const float* W = (g == 0) ? Wq : (g == 1) ? W1 : (g == 2) ? W2
                   : (g == 3) ? W3 : (g == 4) ? Wk : Wv;
    const int n = CT * 16 + (lane & 15);
    const int k0 = ks * 32 + (lane >> 4) * 8;
    ushort out[8];
#pragma unroll
    for (int j = 0; j < 8; ++j) {
        _Float16 h = (_Float16)W[(k0 + j) * 128 + n];
        out[j] = *(ushort*)&h;
    }
    *(uint4*)&wpack[(size_t)(((g * 8 + CT) * 4 + ks) * 64 + lane) * 8] = *(uint4*)out;
}

// ================= attn: gather + softmax + weighted sums (vectorized LDS) =====
__global__ __launch_bounds__(256, 6) void attn_kernel(
    const ushort* __restrict__ qext, const ushort* __restrict__ kv,
    const float* __restrict__ dist, const float* __restrict__ seq,
    const int* __restrict__ idx, ushort* __restrict__ ovec)
{
    __shared__ __align__(16) float dists[32 * LDD];
    __shared__ __align__(16) float seqs[32 * LDS_];
    __shared__ __align__(16) float qe[512];
    __shared__ __align__(16) float attn_s[256];
    __shared__ __align__(16) ushort kvv[32 * 128];

    const int t = threadIdx.x;
    const int n = blockIdx.x;
    const int h = t >> 5, k = t & 31;

    int j = idx[n * 32 + k];
    const uint4* mkp = (const uint4*)(kv + (size_t)j * 256 + h * 16);
    uint4 mk0 = mkp[0], mk1 = mkp[1];

    {   // stage msgv half to LDS: 32 rows x 256B, 8 threads/row
        int r = t >> 3, cc = t & 7;
        int j2 = idx[n * 32 + r];
        const uint4* vp = (const uint4*)(kv + (size_t)j2 * 256 + 128 + cc * 16);
        uint4 v0 = vp[0], v1 = vp[1];
        *(uint4*)&kvv[r * 128 + cc * 16] = v0;
        *(uint4*)&kvv[r * 128 + cc * 16 + 8] = v1;
    }
    {   // dists: b128-aligned rows (stride 36)
        float4 v = *(const float4*)&dist[(size_t)n * 1024 + t * 4];
        int kk = t >> 3, d0 = (t & 7) * 4;
        *(float4*)&dists[kk * LDD + d0] = v;
    }
    if (t < 128) {   // seqs: stride 20
        float4 v = *(const float4*)&seq[(size_t)n * 512 + t * 4];
        int kk = t >> 2, s0 = (t & 3) * 4;
        *(float4*)&seqs[kk * LDS_ + s0] = v;
    }
    if (t < 128) {   // unpack f16 qext[512] -> f32 LDS (layout: h*64 + [48 ext | 16 q])
        uint4 u = *(const uint4*)&qext[(size_t)n * 512 + t * 8];
        float2 a = h2f2(u.x), b = h2f2(u.y), c = h2f2(u.z), d = h2f2(u.w);
        *(float4*)&qe[t * 8]     = make_float4(a.x, a.y, b.x, b.y);
        *(float4*)&qe[t * 8 + 4] = make_float4(c.x, c.y, d.x, d.y);
    }
    __syncthreads();

    {
        const float* qh = &qe[h * 64 + 48];
        float2 p;
        float lg = 0.f;
        p = h2f2(mk0.x); lg += qh[0]  * p.x + qh[1]  * p.y;
        p = h2f2(mk0.y); lg += qh[2]  * p.x + qh[3]  * p.y;
        p = h2f2(mk0.z); lg += qh[4]  * p.x + qh[5]  * p.y;
        p = h2f2(mk0.w); lg += qh[6]  * p.x + qh[7]  * p.y;
        p = h2f2(mk1.x); lg += qh[8]  * p.x + qh[9]  * p.y;
        p = h2f2(mk1.y); lg += qh[10] * p.x + qh[11] * p.y;
        p = h2f2(mk1.z); lg += qh[12] * p.x + qh[13] * p.y;
        p = h2f2(mk1.w); lg += qh[14] * p.x + qh[15] * p.y;
        const float4* dr = (const float4*)&dists[k * LDD];
        const float4* qd = (const float4*)&qe[h * 64];
#pragma unroll
        for (int i = 0; i < 8; ++i) {
            float4 a = dr[i], b = qd[i];
            lg += a.x * b.x + a.y * b.y + a.z * b.z + a.w * b.w;
        }
        const float4* sr = (const float4*)&seqs[k * LDS_];
        const float4* qs2 = (const float4*)&qe[h * 64 + 32];
#pragma unroll
        for (int i = 0; i < 4; ++i) {
            float4 a = sr[i], b = qs2[i];
            lg += a.x * b.x + a.y * b.y + a.z * b.z + a.w * b.w;
        }
        lg *= 0.25f;   // 1/sqrt(ADIM=16)
        float mx = lg;
#pragma unroll
        for (int off = 16; off; off >>= 1) mx = fmaxf(mx, __shfl_xor(mx, off));
        float e = __expf(lg - mx);
        float sum = e;
#pragma unroll
        for (int off = 16; off; off >>= 1) sum += __shfl_xor(sum, off);
        attn_s[t] = e / sum;
    }
    __syncthreads();

    ushort* od = &ovec[(size_t)n * 512];
    {   // wd[h][d=k]: attn broadcast float4, dists column scalar (conflict-free, stride 36)
        float wd = 0.f;
#pragma unroll
        for (int i = 0; i < 8; ++i) {
            float4 a = *(const float4*)&attn_s[h * 32 + i * 4];
            wd += a.x * dists[(i * 4 + 0) * LDD + k] + a.y * dists[(i * 4 + 1) * LDD + k]
                + a.z * dists[(i * 4 + 2) * LDD + k] + a.w * dists[(i * 4 + 3) * LDD + k];
        }
        _Float16 hv = (_Float16)wd;
        od[128 + t] = *(ushort*)&hv;
    }
    if (t < 128) {
        const int h2 = t >> 4, s = t & 15;
        float o = 0.f, ws = 0.f;
#pragma unroll
        for (int i = 0; i < 8; ++i) {
            float4 a = *(const float4*)&attn_s[h2 * 32 + i * 4];
            ushort u0 = kvv[(i * 4 + 0) * 128 + t], u1 = kvv[(i * 4 + 1) * 128 + t];
            ushort u2 = kvv[(i * 4 + 2) * 128 + t], u3 = kvv[(i * 4 + 3) * 128 + t];
            o += a.x * __half2float(*(__half*)&u0) + a.y * __half2float(*(__half*)&u1)
               + a.z * __half2float(*(__half*)&u2) + a.w * __half2float(*(__half*)&u3);
            ws += a.x * seqs[(i * 4 + 0) * LDS_ + s] + a.y * seqs[(i * 4 + 1) * LDS_ + s]
                + a.z * seqs[(i * 4 + 2) * LDS_ + s] + a.w * seqs[(i * 4 + 3) * LDS_ + s];
        }
        _Float16 ho = (_Float16)o, hw = (_Float16)ws;
        od[t] = *(ushort*)&ho;
        od[384 + t] = *(ushort*)&hw;
    }
}

// ================= final: out = features + ovec(f16) @ BigW + cvec =================
__global__ __launch_bounds__(256) void final_kernel(
    const ushort* __restrict__ ovec, const float* __restrict__ BigW,
    const float* __restrict__ cvec, const float* __restrict__ features,
    float* __restrict__ out)
{
    __shared__ __align__(16) float bufA[TM * LDA];
    const int t = threadIdx.x;
    const int node0 = blockIdx.x * TM;
    const int m0 = (t >> 5) * 4;
    const int c0 = (t & 31) * 4;
    float acc[4][4];
#pragma unroll
    for (int mm = 0; mm < 4; ++mm)
#pragma unroll
        for (int cc = 0; cc < 4; ++cc) acc[mm][cc] = 0.f;

    for (int ck = 0; ck < 4; ++ck) {
        __syncthreads();
#pragma unroll
        for (int r = 0; r < 4; ++r) {
            int fid = t + 256 * r;
            int row = fid >> 5, c4 = (fid & 31) * 4;
            uint2 u = *(const uint2*)&ovec[(size_t)(node0 + row) * 512 + ck * 128 + c4];
            float2 a = h2f2(u.x), b = h2f2(u.y);
            *(float4*)&bufA[row * LDA + c4] = make_float4(a.x, a.y, b.x, b.y);
        }
        __syncthreads();
        const float* Wc = BigW + ck * 128 * 128;
#pragma unroll 4
        for (int ic = 0; ic < 32; ++ic) {
            float a[4][4];
#pragma unroll
            for (int mm = 0; mm < 4; ++mm) {
                float4 av = *(const float4*)&bufA[(m0 + mm) * LDA + ic * 4];
                a[mm][0] = av.x; a[mm][1] = av.y; a[mm][2] = av.z; a[mm][3] = av.w;
            }
            float w[4][4];
#pragma unroll
            for (int ii = 0; ii < 4; ++ii) {
                float4 wv = *(const float4*)&Wc[(ic * 4 + ii) * 128 + c0];
                w[ii][0] = wv.x; w[ii][1] = wv.y; w[ii][2] = wv.z; w[ii][3] = wv.w;
            }
#pragma unroll
            for (int mm = 0; mm < 4; ++mm)
#pragma unroll
                for (int ii = 0; ii < 4; ++ii) {
                    float av = a[mm][ii];
#pragma unroll
                    for (int cc = 0; cc < 4; ++cc)
                        acc[mm][cc] = fmaf(av, w[ii][cc], acc[mm][cc]);
                }
        }
    }
    float4 cv = *(const float4*)&cvec[c0];
#pragma unroll
    for (int mm = 0; mm < 4; ++mm) {
        float4 f = *(const float4*)&features[(size_t)(node0 + m0 + mm) * 128 + c0];
        *(float4*)&out[(size_t)(node0 + m0 + mm) * 128 + c0] =
            make_float4(acc[mm][0] + f.x + cv.x, acc[mm][1] + f.y + cv.y,
                        acc[mm][2] + f.z + cv.z, acc[mm][3] + f.w + cv.w);
    }
}

// BigW[512][128]: rows 0-127 = Wo; 128+h*32+d = Wv_dist(d,h)@Wo_h; 384+h*16+s = Wv_seq(s,h)@Wo_h.
__global__ void wprep_kernel(
    const float* __restrict__ Wv, const float* __restrict__ Wo,
    const float* __restrict__ bv, const float* __restrict__ bo,
    float* __restrict__ BigW, float* __restrict__ cvec)
{
    const int r = blockIdx.x;   // 0..511
    const int c = threadIdx.x;  // 0..127
    float s = 0.f;
    if (r < 128) {
        s = Wo[r * 128 + c];
    } else if (r < 384) {
        int x = r - 128; int hh = x >> 5, d = x & 31;
#pragma unroll
        for (int a = 0; a < 16; ++a)
            s += Wv[(128 + d) * 128 + hh * 16 + a] * Wo[(hh * 16 + a) * 128 + c];
    } else {
        int x = r - 384; int hh = x >> 4, ss = x & 15;
#pragma unroll
        for (int a = 0; a < 16; ++a)
            s += Wv[(160 + ss) * 128 + hh * 16 + a] * Wo[(hh * 16 + a) * 128 + c];
    }
    BigW[r * 128 + c] = s;
    if (r == 0) {
        float cv = bo[c];
        for (int jj = 0; jj < 128; ++jj) cv += bv[jj] * Wo[jj * 128 + c];
        cvec[c] = cv;
    }
}

extern "C" void kernel_launch(void* const* d_in, const int* in_sizes, int n_in,
                              void* d_out, int out_size, void* d_ws, size_t ws_size,
                              hipStream_t stream)
{
    const float* features = (const float*)d_in[0];
    const float* dist     = (const float*)d_in[1];
    const float* seq      = (const float*)d_in[2];
    const float* enc      = (const float*)d_in[3];
    const int*   idx      = (const int*)d_in[4];
    const float* W1 = (const float*)d_in[5];
    const float* b1 = (const float*)d_in[6];
    const float* W2 = (const float*)d_in[7];
    const float* b2 = (const float*)d_in[8];
    const float* W3 = (const float*)d_in[9];
    const float* b3 = (const float*)d_in[10];
    const float* Wq = (const float*)d_in[11];
    const float* bq = (const float*)d_in[12];
    const float* Wk = (const float*)d_in[13];
    // d_in[14] = bk: dropped (softmax-invariant)
    const float* Wv = (const float*)d_in[15];
    const float* bv = (const float*)d_in[16];
    const float* Wo = (const float*)d_in[17];
    const float* bo = (const float*)d_in[18];
    float* out = (float*)d_out;

    // Workspace: kv 8 MB | qext 16 MB (f16, [n][h*64+{48 ext,16 q}]) | ovec 16 MB (f16)
    // | BigW 256 KB | cvec | wpack 192 KB.  Total ~40.5 MB (<< 60 MB proven bound).
    char* ws = (char*)d_ws;
    ushort* kv    = (ushort*)ws;                              //  0 MB
    ushort* qext  = (ushort*)(ws + ((size_t)8  << 20));       //  8 MB
    ushort* ovec  = (ushort*)(ws + ((size_t)24 << 20));       // 24 MB
    float*  BigW  = (float*)(ws + ((size_t)40 << 20));        // 40 MB
    float*  cvec  = (float*)(ws + ((size_t)40 << 20) + 262144);
    ushort* wpack = (ushort*)(ws + ((size_t)40 << 20) + 262144 + 512);

    wprep_kernel<<<512, 128, 0, stream>>>(Wv, Wo, bv, bo, BigW, cvec);
    wpack_kernel<<<192, 64, 0, stream>>>(W1, W2, W3, Wq, Wk, Wv, wpack);
    phaseA_kernel<<<NN / TM, 256, 0, stream>>>(
        features, enc, b1, b2, b3, bq, Wk, wpack, qext, kv);
    attn_kernel<<<NN, 256, 0, stream>>>(qext, kv, dist, seq, idx, ovec);
    final_kernel<<<NN / TM, 256, 0, stream>>>(ovec, BigW, cvec, features, out);
}

// Round 8
// 267.077 us; speedup vs baseline: 1.6117x; 1.0151x over previous
//
#include <hip/hip_runtime.h>
#include <hip/hip_fp16.h>
#include <math.h>

#define NN 16384
#define TM 32
#define LDA 132   // f32 LDS row stride (128 + 4 pad)
#define LDH 136   // f16 LDS row stride (128 + 8 pad, keeps 16B alignment)
#define LDDH 40   // dists f16 stride (80 B rows, 16B-aligned)
#define LDSH 24   // seqs f16 stride (48 B rows, 16B-aligned)

typedef unsigned int uint;
typedef unsigned short ushort;
typedef _Float16 half8 __attribute__((ext_vector_type(8)));
typedef float floatx4 __attribute__((ext_vector_type(4)));

__device__ __forceinline__ uint pack2h(float a, float b) {
    _Float16 ha = (_Float16)a, hb = (_Float16)b;
    ushort ua = *(ushort*)&ha, ub = *(ushort*)&hb;
    return (uint)ua | ((uint)ub << 16);
}
__device__ __forceinline__ float2 h2f2(uint u) {
    __half2 h = *(__half2*)&u;
    return __half22float2(h);
}
// one half2·half2 pair accumulated in f32 (compiler emits v_fma_mix_f32)
__device__ __forceinline__ float dot_h2(uint a, uint b, float acc) {
    __half2 ha = *(__half2*)&a, hb = *(__half2*)&b;
    acc += (float)__low2half(ha)  * (float)__low2half(hb);
    acc += (float)__high2half(ha) * (float)__high2half(hb);
    return acc;
}
__device__ __forceinline__ float hval(ushort u) { return (float)*(__half*)&u; }

// ================= phaseA: MFMA f16 fused 6-GEMM chain + qext =================
// A-frag: A[m=lane&15][k=quad*8+j]  B-frag: B[k=quad*8+j][n=lane&15]
// C/D: col=lane&15, row=quad*4+reg (m89-verified).

struct Acc4 { floatx4 a[4]; };

template<bool RELUA>
__device__ __forceinline__ Acc4 mfma_gemm(const ushort* Ab, const half8* wp, int lane, int w)
{
    const int m  = (w & 1) * 16 + (lane & 15);
    const int kq = (lane >> 4) * 8;
    const int cg = w >> 1;
    half8 afr[4];
#pragma unroll
    for (int ks = 0; ks < 4; ++ks) {
        afr[ks] = *(const half8*)&Ab[m * LDH + ks * 32 + kq];
        if (RELUA) {
#pragma unroll
            for (int j = 0; j < 8; ++j)
                afr[ks][j] = afr[ks][j] > (_Float16)0.f ? afr[ks][j] : (_Float16)0.f;
        }
    }
    Acc4 r;
#pragma unroll
    for (int ct = 0; ct < 4; ++ct) {
        const int CT = cg * 4 + ct;
        floatx4 acc = {0.f, 0.f, 0.f, 0.f};
#pragma unroll
        for (int ks = 0; ks < 4; ++ks) {
            half8 bfr = wp[(CT * 4 + ks) * 64 + lane];
            acc = __builtin_amdgcn_mfma_f32_16x16x32_f16(afr[ks], bfr, acc, 0, 0, 0);
        }
        r.a[ct] = acc;
    }
    return r;
}

template<bool HAS_BIAS, bool RELU, bool HAS_ENC, bool F16OUT>
__device__ __forceinline__ void epilogue(const Acc4& ac, const float* __restrict__ bias,
    const float* __restrict__ enc, ushort* dst16, float* dst32,
    int node0, int lane, int w)
{
    const int row0 = (w & 1) * 16 + ((lane >> 4) << 2);
    const int cg = w >> 1;
#pragma unroll
    for (int ct = 0; ct < 4; ++ct) {
        const int col = (cg * 4 + ct) * 16 + (lane & 15);
        float bb = HAS_BIAS ? bias[col] : 0.f;
#pragma unroll
        for (int r = 0; r < 4; ++r) {
            float x = ac.a[ct][r] + bb;
            if (RELU) x = fmaxf(x, 0.f);
            if (HAS_ENC) x += enc[(size_t)(node0 + row0 + r) * 128 + col];
            if (F16OUT) {
                _Float16 h = (_Float16)x;
                dst16[(row0 + r) * LDH + col] = *(ushort*)&h;
            } else {
                dst32[(row0 + r) * LDA + col] = x;
            }
        }
    }
}

__global__ __launch_bounds__(256) void phaseA_kernel(
    const float* __restrict__ features, const float* __restrict__ enc,
    const float* __restrict__ b1, const float* __restrict__ b2,
    const float* __restrict__ b3, const float* __restrict__ bq,
    const float* __restrict__ Wk, const ushort* __restrict__ wpack,
    ushort* __restrict__ qext, ushort* __restrict__ kv)
{
    __shared__ __align__(16) ushort bufA[TM * LDH];
    __shared__ __align__(16) ushort bufB[TM * LDH];
    __shared__ __align__(16) float  qstage[TM * LDA];
    __shared__ __align__(16) float  wk[48 * 128];
    ushort* vstage = (ushort*)qstage;

    const int t = threadIdx.x;
    const int lane = t & 63, w = t >> 6;
    const int node0 = blockIdx.x * TM;

    const half8* wpQ = (const half8*)(wpack + 0 * 16384);
    const half8* wp1 = (const half8*)(wpack + 1 * 16384);
    const half8* wp2 = (const half8*)(wpack + 2 * 16384);
    const half8* wp3 = (const half8*)(wpack + 3 * 16384);
    const half8* wpK = (const half8*)(wpack + 4 * 16384);
    const half8* wpV = (const half8*)(wpack + 5 * 16384);

#pragma unroll
    for (int r = 0; r < 4; ++r) {
        int fid = t + 256 * r;
        int row = fid >> 5, c4 = (fid & 31) * 4;
        float4 v = *(const float4*)&features[(size_t)(node0 + row) * 128 + c4];
        uint2 h = make_uint2(pack2h(v.x, v.y), pack2h(v.z, v.w));
        *(uint2*)&bufA[row * LDH + c4] = h;
    }
#pragma unroll
    for (int r = 0; r < 6; ++r) {
        int fid = t + 256 * r;
        *(float4*)&wk[fid * 4] = *(const float4*)&Wk[128 * 128 + fid * 4];
    }
    __syncthreads();

    Acc4 aQ = mfma_gemm<false>(bufA, wpQ, lane, w);          // q = F@Wq
    Acc4 a1 = mfma_gemm<true >(bufA, wp1, lane, w);          // relu(F)@W1
    epilogue<true, false, false, false>(aQ, bq, nullptr, nullptr, qstage, node0, lane, w);
    epilogue<true, true,  false, true >(a1, b1, nullptr, bufB, nullptr, node0, lane, w);
    __syncthreads();

    Acc4 a2 = mfma_gemm<false>(bufB, wp2, lane, w);          // h1@W2

    // fused qext: per (node m, head hh): 48 ext dots + q copy, f16 out
    {
        const int m = t >> 3, hh = t & 7;
        float q[16];
#pragma unroll
        for (int jj = 0; jj < 4; ++jj)
            *(float4*)&q[jj * 4] = *(const float4*)&qstage[m * LDA + hh * 16 + jj * 4];
        ushort* dst = &qext[(size_t)(node0 + m) * 512 + hh * 64];
#pragma unroll
        for (int x0 = 0; x0 < 48; x0 += 8) {
            float res[8];
#pragma unroll
            for (int xx = 0; xx < 8; ++xx) {
                const float* wr = &wk[(x0 + xx) * 128 + hh * 16];
                float s = 0.f;
#pragma unroll
                for (int jj = 0; jj < 4; ++jj) {
                    float4 wv = *(const float4*)&wr[jj * 4];
                    s += q[jj*4+0]*wv.x + q[jj*4+1]*wv.y + q[jj*4+2]*wv.z + q[jj*4+3]*wv.w;
                }
                res[xx] = s;
            }
            *(uint4*)&dst[x0] = make_uint4(pack2h(res[0], res[1]), pack2h(res[2], res[3]),
                                           pack2h(res[4], res[5]), pack2h(res[6], res[7]));
        }
        *(uint4*)&dst[48] = make_uint4(pack2h(q[0], q[1]),  pack2h(q[2], q[3]),
                                       pack2h(q[4], q[5]),  pack2h(q[6], q[7]));
        *(uint4*)&dst[56] = make_uint4(pack2h(q[8], q[9]),  pack2h(q[10], q[11]),
                                       pack2h(q[12], q[13]), pack2h(q[14], q[15]));
    }
    epilogue<true, true, false, true>(a2, b2, nullptr, bufA, nullptr, node0, lane, w);
    __syncthreads();

    Acc4 a3 = mfma_gemm<false>(bufA, wp3, lane, w);          // h2@W3
    epilogue<true, true, true, true>(a3, b3, enc, bufB, nullptr, node0, lane, w);  // msg
    __syncthreads();

    Acc4 aK = mfma_gemm<false>(bufB, wpK, lane, w);          // msg@Wk[:128]
    Acc4 aV = mfma_gemm<false>(bufB, wpV, lane, w);          // msg@Wv[:128]
    epilogue<false, false, false, true>(aK, nullptr, nullptr, bufA,   nullptr, node0, lane, w);
    epilogue<false, false, false, true>(aV, nullptr, nullptr, vstage, nullptr, node0, lane, w);
    __syncthreads();

    {
        int row = t >> 3, c16 = (t & 7) * 16;
        size_t kbase = (size_t)(node0 + row) * 256;
        *(uint4*)&kv[kbase + c16]           = *(const uint4*)&bufA[row * LDH + c16];
        *(uint4*)&kv[kbase + c16 + 8]       = *(const uint4*)&bufA[row * LDH + c16 + 8];
        *(uint4*)&kv[kbase + 128 + c16]     = *(const uint4*)&vstage[row * LDH + c16];
        *(uint4*)&kv[kbase + 128 + c16 + 8] = *(const uint4*)&vstage[row * LDH + c16 + 8];
    }
}

// ===== merged prep: BigW/cvec (blocks 0..511) + wpack (blocks 512..703) =====
__global__ void prep_kernel(
    const float* __restrict__ Wv, const float* __restrict__ Wo,
    const float* __restrict__ bv, const float* __restrict__ bo,
    const float* __restrict__ W1, const float* __restrict__ W2,
    const float* __restrict__ W3, const float* __restrict__ Wq,
    const float* __restrict__ Wk,
    float* __restrict__ BigW, float* __restrict__ cvec,
    ushort* __restrict__ wpack)
{
    const int r = blockIdx.x;
    const int c = threadIdx.x;
    if (r < 512) {
        float s = 0.f;
        if (r < 128) {
            s = Wo[r * 128 + c];
        } else if (r < 384) {
            int x = r - 128; int hh = x >> 5, d = x & 31;
#pragma unroll
            for (int a = 0; a < 16; ++a)
                s += Wv[(128 + d) * 128 + hh * 16 + a] * Wo[(hh * 16 + a) * 128 + c];
        } else {
            int x = r - 384; int hh = x >> 4, ss = x & 15;
#pragma unroll
            for (int a = 0; a < 16; ++a)
                s += Wv[(160 + ss) * 128 + hh * 16 + a] * Wo[(hh * 16 + a) * 128 + c];
        }
        BigW[r * 128 + c] = s;
        if (r == 0) {
            float cv = bo[c];
            for (int jj = 0; jj < 128; ++jj) cv += bv[jj] * Wo[jj * 128 + c];
            cvec[c] = cv;
        }
    } else {
        if (c >= 64) return;
        const int bb = r - 512;          // 0..191
        const int g = bb >> 5;
        const int rem = bb & 31;
        const int CT = rem >> 2, ks = rem & 3;
        const float* W = (g == 0) ? Wq : (g == 1) ? W1 : (g == 2) ? W2
                       : (g == 3) ? W3 : (g == 4) ? Wk : Wv;
        const int n = CT * 16 + (c & 15);
        const int k0 = ks * 32 + (c >> 4) * 8;
        ushort out[8];
#pragma unroll
        for (int j = 0; j < 8; ++j) {
            _Float16 h = (_Float16)W[(k0 + j) * 128 + n];
            out[j] = *(ushort*)&h;
        }
        *(uint4*)&wpack[(size_t)(((g * 8 + CT) * 4 + ks) * 64 + c) * 8] = *(uint4*)out;
    }
}

// ========= attn: all-f16 LDS operands (v_fma_mix), balanced epilogue =========
__global__ __launch_bounds__(256, 6) void attn_kernel(
    const ushort* __restrict__ qext, const ushort* __restrict__ kv,
    const float* __restrict__ dist, const float* __restrict__ seq,
    const int* __restrict__ idx, ushort* __restrict__ ovec)
{
    __shared__ __align__(16) ushort distsH[32 * LDDH];
    __shared__ __align__(16) ushort seqsH[32 * LDSH];
    __shared__ __align__(16) ushort qeH[512];       // [h*64 + {48 ext | 16 q}]
    __shared__ __align__(16) float attn_s[256];
    __shared__ __align__(16) ushort kvv[32 * 128];

    const int t = threadIdx.x;
    const int n = blockIdx.x;
    const int h = t >> 5, k = t & 31;

    int j = idx[n * 32 + k];
    const uint4* mkp = (const uint4*)(kv + (size_t)j * 256 + h * 16);
    uint4 mk0 = mkp[0], mk1 = mkp[1];

    {   // msgv half -> LDS rows (8 threads/row)
        int r = t >> 3, cc = t & 7;
        int j2 = idx[n * 32 + r];
        const uint4* vp = (const uint4*)(kv + (size_t)j2 * 256 + 128 + cc * 16);
        uint4 v0 = vp[0], v1 = vp[1];
        *(uint4*)&kvv[r * 128 + cc * 16] = v0;
        *(uint4*)&kvv[r * 128 + cc * 16 + 8] = v1;
    }
    {   // dists -> f16, stride 40 halves
        float4 v = *(const float4*)&dist[(size_t)n * 1024 + t * 4];
        int kk = t >> 3, d0 = (t & 7) * 4;
        *(uint2*)&distsH[kk * LDDH + d0] = make_uint2(pack2h(v.x, v.y), pack2h(v.z, v.w));
    }
    if (t < 128) {   // seqs -> f16, stride 24 halves
        float4 v = *(const float4*)&seq[(size_t)n * 512 + t * 4];
        int kk = t >> 2, s0 = (t & 3) * 4;
        *(uint2*)&seqsH[kk * LDSH + s0] = make_uint2(pack2h(v.x, v.y), pack2h(v.z, v.w));
    }
    if (t < 64)      // qext stays f16 — raw copy, no unpack
        *(uint4*)&qeH[t * 8] = *(const uint4*)&qext[(size_t)n * 512 + t * 8];
    __syncthreads();

    {   // logits: 64 mix-fma + 14 b128 LDS reads
        float lg = 0.f;
        const uint4* qhp = (const uint4*)&qeH[h * 64 + 48];
        uint4 q0 = qhp[0], q1 = qhp[1];
        lg = dot_h2(mk0.x, q0.x, lg); lg = dot_h2(mk0.y, q0.y, lg);
        lg = dot_h2(mk0.z, q0.z, lg); lg = dot_h2(mk0.w, q0.w, lg);
        lg = dot_h2(mk1.x, q1.x, lg); lg = dot_h2(mk1.y, q1.y, lg);
        lg = dot_h2(mk1.z, q1.z, lg); lg = dot_h2(mk1.w, q1.w, lg);
        const uint4* drp = (const uint4*)&distsH[k * LDDH];
        const uint4* qdp = (const uint4*)&qeH[h * 64];
#pragma unroll
        for (int i = 0; i < 4; ++i) {
            uint4 a = drp[i], b = qdp[i];
            lg = dot_h2(a.x, b.x, lg); lg = dot_h2(a.y, b.y, lg);
            lg = dot_h2(a.z, b.z, lg); lg = dot_h2(a.w, b.w, lg);
        }
        const uint4* srp = (const uint4*)&seqsH[k * LDSH];
        const uint4* qsp = (const uint4*)&qeH[h * 64 + 32];
#pragma unroll
        for (int i = 0; i < 2; ++i) {
            uint4 a = srp[i], b = qsp[i];
            lg = dot_h2(a.x, b.x, lg); lg = dot_h2(a.y, b.y, lg);
            lg = dot_h2(a.z, b.z, lg); lg = dot_h2(a.w, b.w, lg);
        }
        lg *= 0.25f;   // 1/sqrt(ADIM=16)
        float mx = lg;
#pragma unroll
        for (int off = 16; off; off >>= 1) mx = fmaxf(mx, __shfl_xor(mx, off));
        float e = __expf(lg - mx);
        float sum = e;
#pragma unroll
        for (int off = 16; off; off >>= 1) sum += __shfl_xor(sum, off);
        attn_s[t] = e / sum;
    }
    __syncthreads();

    ushort* od = &ovec[(size_t)n * 512];
    {   // wd: all 256 threads (d = k)
        float wd = 0.f;
#pragma unroll
        for (int i = 0; i < 8; ++i) {
            float4 a = *(const float4*)&attn_s[h * 32 + i * 4];
            wd += a.x * hval(distsH[(i * 4 + 0) * LDDH + k])
                + a.y * hval(distsH[(i * 4 + 1) * LDDH + k])
                + a.z * hval(distsH[(i * 4 + 2) * LDDH + k])
                + a.w * hval(distsH[(i * 4 + 3) * LDDH + k]);
        }
        _Float16 hv = (_Float16)wd;
        od[128 + t] = *(ushort*)&hv;
    }
    if (t < 128) {   // o: lower half
        const int h2 = t >> 4;
        float o = 0.f;
#pragma unroll
        for (int i = 0; i < 8; ++i) {
            float4 a = *(const float4*)&attn_s[h2 * 32 + i * 4];
            o += a.x * hval(kvv[(i * 4 + 0) * 128 + t])
               + a.y * hval(kvv[(i * 4 + 1) * 128 + t])
               + a.z * hval(kvv[(i * 4 + 2) * 128 + t])
               + a.w * hval(kvv[(i * 4 + 3) * 128 + t]);
        }
        _Float16 ho = (_Float16)o;
        od[t] = *(ushort*)&ho;
    } else {         // ws: upper half
        const int tt = t - 128;
        const int h2 = tt >> 4, s = tt & 15;
        float ws = 0.f;
#pragma unroll
        for (int i = 0; i < 8; ++i) {
            float4 a = *(const float4*)&attn_s[h2 * 32 + i * 4];
            ws += a.x * hval(seqsH[(i * 4 + 0) * LDSH + s])
                + a.y * hval(seqsH[(i * 4 + 1) * LDSH + s])
                + a.z * hval(seqsH[(i * 4 + 2) * LDSH + s])
                + a.w * hval(seqsH[(i * 4 + 3) * LDSH + s]);
        }
        _Float16 hw = (_Float16)ws;
        od[384 + tt] = *(ushort*)&hw;
    }
}

// ================= final: out = features + ovec(f16) @ BigW + cvec =================
__global__ __launch_bounds__(256) void final_kernel(
    const ushort* __restrict__ ovec, const float* __restrict__ BigW,
    const float* __restrict__ cvec, const float* __restrict__ features,
    float* __restrict__ out)
{
    __shared__ __align__(16) float bufA[TM * LDA];
    const int t = threadIdx.x;
    const int node0 = blockIdx.x * TM;
    const int m0 = (t >> 5) * 4;
    const int c0 = (t & 31) * 4;
    float acc[4][4];
#pragma unroll
    for (int mm = 0; mm < 4; ++mm)
#pragma unroll
        for (int cc = 0; cc < 4; ++cc) acc[mm][cc] = 0.f;

    for (int ck = 0; ck < 4; ++ck) {
        __syncthreads();
#pragma unroll
        for (int r = 0; r < 4; ++r) {
            int fid = t + 256 * r;
            int row = fid >> 5, c4 = (fid & 31) * 4;
            uint2 u = *(const uint2*)&ovec[(size_t)(node0 + row) * 512 + ck * 128 + c4];
            float2 a = h2f2(u.x), b = h2f2(u.y);
            *(float4*)&bufA[row * LDA + c4] = make_float4(a.x, a.y, b.x, b.y);
        }
        __syncthreads();
        const float* Wc = BigW + ck * 128 * 128;
#pragma unroll 4
        for (int ic = 0; ic < 32; ++ic) {
            float a[4][4];
#pragma unroll
            for (int mm = 0; mm < 4; ++mm) {
                float4 av = *(const float4*)&bufA[(m0 + mm) * LDA + ic * 4];
                a[mm][0] = av.x; a[mm][1] = av.y; a[mm][2] = av.z; a[mm][3] = av.w;
            }
            float w[4][4];
#pragma unroll
            for (int ii = 0; ii < 4; ++ii) {
                float4 wv = *(const float4*)&Wc[(ic * 4 + ii) * 128 + c0];
                w[ii][0] = wv.x; w[ii][1] = wv.y; w[ii][2] = wv.z; w[ii][3] = wv.w;
            }
#pragma unroll
            for (int mm = 0; mm < 4; ++mm)
#pragma unroll
                for (int ii = 0; ii < 4; ++ii) {
                    float av = a[mm][ii];
#pragma unroll
                    for (int cc = 0; cc < 4; ++cc)
                        acc[mm][cc] = fmaf(av, w[ii][cc], acc[mm][cc]);
                }
        }
    }
    float4 cv = *(const float4*)&cvec[c0];
#pragma unroll
    for (int mm = 0; mm < 4; ++mm) {
        float4 f = *(const float4*)&features[(size_t)(node0 + m0 + mm) * 128 + c0];
        *(float4*)&out[(size_t)(node0 + m0 + mm) * 128 + c0] =
            make_float4(acc[mm][0] + f.x + cv.x, acc[mm][1] + f.y + cv.y,
                        acc[mm][2] + f.z + cv.z, acc[mm][3] + f.w + cv.w);
    }
}

extern "C" void kernel_launch(void* const* d_in, const int* in_sizes, int n_in,
                              void* d_out, int out_size, void* d_ws, size_t ws_size,
                              hipStream_t stream)
{
    const float* features = (const float*)d_in[0];
    const float* dist     = (const float*)d_in[1];
    const float* seq      = (const float*)d_in[2];
    const float* enc      = (const float*)d_in[3];
    const int*   idx      = (const int*)d_in[4];
    const float* W1 = (const float*)d_in[5];
    const float* b1 = (const float*)d_in[6];
    const float* W2 = (const float*)d_in[7];
    const float* b2 = (const float*)d_in[8];
    const float* W3 = (const float*)d_in[9];
    const float* b3 = (const float*)d_in[10];
    const float* Wq = (const float*)d_in[11];
    const float* bq = (const float*)d_in[12];
    const float* Wk = (const float*)d_in[13];
    // d_in[14] = bk: dropped (softmax-invariant)
    const float* Wv = (const float*)d_in[15];
    const float* bv = (const float*)d_in[16];
    const float* Wo = (const float*)d_in[17];
    const float* bo = (const float*)d_in[18];
    float* out = (float*)d_out;

    // Workspace: kv 8 | qext 16 | ovec 16 | BigW 256K | cvec | wpack 192K  (~40.5 MB)
    char* ws = (char*)d_ws;
    ushort* kv    = (ushort*)ws;
    ushort* qext  = (ushort*)(ws + ((size_t)8  << 20));
    ushort* ovec  = (ushort*)(ws + ((size_t)24 << 20));
    float*  BigW  = (float*)(ws + ((size_t)40 << 20));
    float*  cvec  = (float*)(ws + ((size_t)40 << 20) + 262144);
    ushort* wpack = (ushort*)(ws + ((size_t)40 << 20) + 262144 + 512);

    prep_kernel<<<704, 128, 0, stream>>>(Wv, Wo, bv, bo, W1, W2, W3, Wq, Wk,
                                         BigW, cvec, wpack);
    phaseA_kernel<<<NN / TM, 256, 0, stream>>>(
        features, enc, b1, b2, b3, bq, Wk, wpack, qext, kv);
    attn_kernel<<<NN, 256, 0, stream>>>(qext, kv, dist, seq, idx, ovec);
    final_kernel<<<NN / TM, 256, 0, stream>>>(ovec, BigW, cvec, features, out);
}